// Round 1
// baseline (7632.394 us; speedup 1.0000x reference)
//
#include <hip/hip_runtime.h>
#include <cstdint>
#include <cstddef>

// RNNDecoder: B=32, T=64, S=400, V=50257, DW=DM=DE=512, DK=64, POOL=2
// Persistent-kernel version: the entire 64-step recurrence runs in ONE
// cooperative kernel (128 blocks x 512 threads) with device-wide barriers
// between the GEMM phase and the attention phase of each step.
// Rationale: per-step work is ~1-3 us but per-step kernel-pair cost was
// ~44 us -> launch/ramp/drain-bound. Init kernels unchanged.

#define PAD_ID_C 50256

typedef float f32x4 __attribute__((ext_vector_type(4)));
typedef short bf16x8 __attribute__((ext_vector_type(8)));

__device__ __forceinline__ unsigned short f2bf(float x){
  union { float f; unsigned u; } v; v.f = x;
  unsigned r = (v.u + 0x7FFFu + ((v.u >> 16) & 1u)) >> 16;
  return (unsigned short)r;
}
__device__ __forceinline__ float bf2f(unsigned short h){
  union { unsigned u; float f; } v; v.u = ((unsigned)h) << 16; return v.f;
}
__device__ __forceinline__ float sigm_(float x){ return 1.f/(1.f+__expf(-x)); }
__device__ __forceinline__ float tanh_(float x){ float e=__expf(2.f*x); return 1.f - 2.f/(e+1.f); }

// packed A-activation index for [32][512] src -> tiles (mt,kt,lane,8)
__device__ __forceinline__ int pkidx(int b, int d){
  return ((((b>>4)*16) + (d>>5))*64 + (((d>>3)&3)*16) + (b&15))*8 + (d&7);
}

// ---------------- init kernels (unchanged except k_h0 zeroes barrier) ----------------

__global__ void k_pack(const float* __restrict__ W, unsigned short* __restrict__ pk, int N, int K){
  int ktc = K >> 5;
  int gid = blockIdx.x*256 + threadIdx.x;
  int total = (N>>4)*ktc*64;
  if (gid >= total) return;
  int lane = gid & 63;
  int rem = gid >> 6;
  int kt = rem % ktc, nt = rem / ktc;
  int k0 = kt*32 + (lane>>4)*8;
  int n  = nt*16 + (lane&15);
  #pragma unroll
  for (int j=0;j<8;j++) pk[gid*8+j] = f2bf(W[(k0+j)*N + n]);
}

__global__ void k_misc(const float* __restrict__ Wq, unsigned short* __restrict__ wq_bf,
                       float* __restrict__ cov0){
  int idx = blockIdx.x*256 + threadIdx.x;
  if (idx < 512*64) wq_bf[idx] = f2bf(Wq[idx]);
  else if (idx < 512*64 + 32*400) cov0[idx - 512*64] = 0.f;
}

__global__ void k_emb(const int* __restrict__ tgt, const float* __restrict__ word_emb,
                      unsigned short* __restrict__ emb_pk){
  int bid = blockIdx.x;           // t*32+b
  int t = bid >> 5, b = bid & 31;
  int token = tgt[b*64 + t];
  const float* src = word_emb + (size_t)token*512;
  for (int d = threadIdx.x; d < 512; d += 256){
    int idx = (((t*2 + (b>>4))*16 + (d>>5))*64 + ((d>>3)&3)*16 + (b&15))*8 + (d&7);
    emb_pk[idx] = f2bf(src[d]);
  }
}

__global__ void k_encbf(const float* __restrict__ enc, unsigned short* __restrict__ enc_bf){
  int idx = blockIdx.x*256 + threadIdx.x;
  if (idx < 32*400*512) enc_bf[idx] = f2bf(enc[idx]);
}

__global__ void k_pre(const float* __restrict__ enc, const float* __restrict__ Wc,
                      unsigned short* __restrict__ pre_t){
  int bs = blockIdx.x;            // b*400+s
  int b = bs / 400, s = bs % 400;
  int k = threadIdx.x;            // 64 threads
  const float* e = enc + (size_t)bs*512;
  float acc = 0.f;
  for (int d=0; d<512; d++) acc += e[d]*Wc[d*64+k];
  pre_t[(b*64+k)*400 + s] = f2bf(acc);
}

// h0 = tanh(hidden@W_init + b_init); ctx=0; also zero the grid barrier counter
__global__ void k_h0(const float* __restrict__ hidden, const float* __restrict__ W_init,
                     const float* __restrict__ b_init,
                     float* __restrict__ h_f32, unsigned short* __restrict__ h_pk,
                     float* __restrict__ ctx_f32, unsigned short* __restrict__ ctx_pk,
                     int* __restrict__ bar){
  int b = blockIdx.x, jj = threadIdx.x;   // 32 x 512
  if (b == 0 && jj == 0) *bar = 0;
  const float* hv = hidden + b*512;
  float acc = 0.f;
  for (int d=0; d<512; d++) acc += hv[d]*W_init[d*512+jj];
  float h = tanh_(acc + b_init[jj]);
  h_f32[b*512+jj] = h;
  h_pk[pkidx(b,jj)] = f2bf(h);
  ctx_f32[b*512+jj] = 0.f;
  ctx_pk[b*512+jj] = 0;   // zeros in any layout are zeros
}

// ---------------- persistent step kernel ----------------

struct PP {
  const unsigned short* emb_pk;
  unsigned short* h_pk;
  unsigned short* ctx_pk;
  const unsigned short* wx_pk;
  const unsigned short* wh_pk;
  const unsigned short* wr_pk;
  float* gxbuf; float* ghbuf; float* robuf;
  float* hA; float* hB;            // ping-pong h_f32 slots (hA = slot 0, written by k_h0)
  float* ctx_f32;
  const float* W_copy; const float* b_copy;
  float* out_gate;
  const float* bx; const float* bh; const float* b_read;
  float* cov_base;
  const unsigned short* pre_t; const unsigned short* wq_bf;
  const float* w_cov; const float* v_att;
  const unsigned short* enc_bf; const int* src_seq;
  float* out_pred; float* out_attnlast; float* out_ctxf;
  float* out_copypred; float* out_covloss;
  int* bar;
};

// Monotonic grid barrier. Counter zeroed by k_h0 each launch (graph replay safe).
// Relaxed spin (scoped atomic loads bypass non-coherent L2) + agent fences for
// release/acquire so cross-XCD data written before the barrier is visible after.
__device__ __forceinline__ void gridbar(int* bar, int target){
  __syncthreads();
  if (threadIdx.x == 0){
    __threadfence();   // release: write back this XCD's dirty lines
    __hip_atomic_fetch_add(bar, 1, __ATOMIC_RELAXED, __HIP_MEMORY_SCOPE_AGENT);
    while (__hip_atomic_load(bar, __ATOMIC_RELAXED, __HIP_MEMORY_SCOPE_AGENT) < target)
      __builtin_amdgcn_s_sleep(2);
    __threadfence();   // acquire: invalidate stale lines before consuming
  }
  __syncthreads();
}

__global__ __launch_bounds__(512,1) void k_steps(PP p){
  __shared__ float h_s[512];
  __shared__ float hq_part[8][64];
  __shared__ float hq_s[64];
  __shared__ float wv_s[128];
  __shared__ float p_s[400];
  __shared__ float red[512];
  __shared__ float cred[4][128];

  const int tid = threadIdx.x;
  const int b_at = blockIdx.x >> 2, g = blockIdx.x & 3;
  int nbar = 0;

  for (int t = 0; t <= 64; ++t){
    // h ping-pong: hr = h(t-1) (attn(t-1) wrote slot t&1; k_h0 wrote slot 0)
    const float* hr = (t & 1) ? p.hB : p.hA;
    float*       hw = (t & 1) ? p.hA : p.hB;

    // ---------------- GEMM phase ----------------
    {
      int wib  = tid >> 6;               // wave in block, 0..7
      int lane = tid & 63;
      int wv = wib*128 + blockIdx.x;     // spread jobs across all 128 blocks
      if (wib < 4){
        if (wv < 384){
          if (t < 64){
            int isGh = (wv >= 192);
            int ww = isGh ? wv-192 : wv;
            int nt = ww % 96, mt = ww / 96;
            f32x4 acc = {0.f,0.f,0.f,0.f};
            if (!isGh){
              const bf16x8* wp = (const bf16x8*)p.wx_pk + (size_t)(nt*32)*64 + lane;
              const bf16x8* ae = (const bf16x8*)p.emb_pk + (size_t)((t*2+mt)*16)*64 + lane;
              const bf16x8* ac = (const bf16x8*)p.ctx_pk + (size_t)(mt*16)*64 + lane;
              #pragma unroll
              for (int kt=0; kt<16; kt++)
                acc = __builtin_amdgcn_mfma_f32_16x16x32_bf16(ae[kt*64], wp[kt*64], acc, 0,0,0);
              #pragma unroll
              for (int kt=0; kt<16; kt++)
                acc = __builtin_amdgcn_mfma_f32_16x16x32_bf16(ac[kt*64], wp[(16+kt)*64], acc, 0,0,0);
              int row = mt*16 + (lane>>4)*4, col = nt*16 + (lane&15);
              #pragma unroll
              for (int i=0;i<4;i++) p.gxbuf[(row+i)*1536 + col] = acc[i];
            } else {
              const bf16x8* wp = (const bf16x8*)p.wh_pk + (size_t)(nt*16)*64 + lane;
              const bf16x8* ah = (const bf16x8*)p.h_pk + (size_t)(mt*16)*64 + lane;
              #pragma unroll
              for (int kt=0; kt<16; kt++)
                acc = __builtin_amdgcn_mfma_f32_16x16x32_bf16(ah[kt*64], wp[kt*64], acc, 0,0,0);
              int row = mt*16 + (lane>>4)*4, col = nt*16 + (lane&15);
              #pragma unroll
              for (int i=0;i<4;i++) p.ghbuf[(row+i)*1536 + col] = acc[i];
            }
          }
        } else if (wv < 448){
          if (t > 0){
            int i = wv - 384;
            int nt = i % 32, mt = i / 32;
            f32x4 acc = {0.f,0.f,0.f,0.f};
            const bf16x8* wp = (const bf16x8*)p.wr_pk + (size_t)(nt*48)*64 + lane;
            const bf16x8* ae = (const bf16x8*)p.emb_pk + (size_t)(((t-1)*2+mt)*16)*64 + lane;
            const bf16x8* ah = (const bf16x8*)p.h_pk + (size_t)(mt*16)*64 + lane;
            const bf16x8* ac = (const bf16x8*)p.ctx_pk + (size_t)(mt*16)*64 + lane;
            #pragma unroll
            for (int kt=0; kt<16; kt++)
              acc = __builtin_amdgcn_mfma_f32_16x16x32_bf16(ae[kt*64], wp[kt*64], acc, 0,0,0);
            #pragma unroll
            for (int kt=0; kt<16; kt++)
              acc = __builtin_amdgcn_mfma_f32_16x16x32_bf16(ah[kt*64], wp[(16+kt)*64], acc, 0,0,0);
            #pragma unroll
            for (int kt=0; kt<16; kt++)
              acc = __builtin_amdgcn_mfma_f32_16x16x32_bf16(ac[kt*64], wp[(32+kt)*64], acc, 0,0,0);
            int row = mt*16 + (lane>>4)*4, col = nt*16 + (lane&15);
            #pragma unroll
            for (int i=0;i<4;i++) p.robuf[(row+i)*512 + col] = acc[i];
          }
        } else if (wv < 480){
          if (t > 0){
            int b = wv - 448;   // copy_gate(t-1) = sigmoid([h(t-1),ctx(t-1)]@W_copy + b_copy)
            float acc = 0.f;
            #pragma unroll
            for (int i=0;i<16;i++){
              int j = i*64 + lane;
              float x = (j < 512) ? hr[b*512+j] : p.ctx_f32[b*512 + (j-512)];
              acc += x * p.W_copy[j];
            }
            for (int off=32; off>0; off>>=1) acc += __shfl_down(acc, off, 64);
            if (lane == 0) p.out_gate[b*64 + (t-1)] = sigm_(acc + p.b_copy[0]);
          }
        }
      }
    }
    gridbar(p.bar, (++nbar)*128);

    // ---------------- ATTN phase ----------------
    if (t < 64){
      const float* cov_r = p.cov_base + (t & 1)*12800;
      float* cov_w = p.cov_base + ((t+1) & 1)*12800;
      const int b = b_at;

      // phase 0: GRU combine -> h(t)
      {
        int jj = tid;
        float gx0 = p.gxbuf[b*1536+jj], gx1 = p.gxbuf[b*1536+512+jj], gx2 = p.gxbuf[b*1536+1024+jj];
        float gh0 = p.ghbuf[b*1536+jj], gh1 = p.ghbuf[b*1536+512+jj], gh2 = p.ghbuf[b*1536+1024+jj];
        float r = sigm_(gx0 + p.bx[jj]     + gh0 + p.bh[jj]);
        float z = sigm_(gx1 + p.bx[512+jj] + gh1 + p.bh[512+jj]);
        float n = tanh_(gx2 + p.bx[1024+jj] + r*(gh2 + p.bh[1024+jj]));
        float hold = hr[b*512+jj];
        float hn = (1.f - z)*n + z*hold;
        h_s[jj] = hn;
        if (g == 0){ hw[b*512+jj] = hn; p.h_pk[pkidx(b,jj)] = f2bf(hn); }
      }
      if (tid < 128) wv_s[tid] = (tid < 64) ? p.w_cov[tid] : p.v_att[tid-64];
      // phase 0b: maxout of readout(t-1)
      if (t > 0 && g == 0 && tid < 256){
        float r0 = p.robuf[b*512 + 2*tid]     + p.b_read[2*tid];
        float r1 = p.robuf[b*512 + 2*tid + 1] + p.b_read[2*tid + 1];
        p.out_pred[((size_t)b*64 + (t-1))*256 + tid] = fmaxf(r0, r1);
      }
      __syncthreads();

      // phase 1: hq = h @ Wq  (64 outputs, 8-way k-split)
      {
        int k = tid & 63, pr = tid >> 6;
        float a = 0.f;
        const unsigned short* wq = p.wq_bf + k;
        for (int d = pr*64; d < pr*64 + 64; d++) a += h_s[d]*bf2f(wq[d*64]);
        hq_part[pr][k] = a;
      }
      __syncthreads();
      if (tid < 64){
        float a = 0.f;
        #pragma unroll
        for (int pr=0;pr<8;pr++) a += hq_part[pr][tid];
        hq_s[tid] = a;
      }
      __syncthreads();

      // phase 2: scores + exp (no max-subtraction: |score| < ~1)
      float c_old = 0.f, p_val = 0.f;
      int s = tid;
      if (s < 400){
        c_old = cov_r[b*400+s];
        float a = 0.f;
        const unsigned short* pp2 = p.pre_t + (b*64)*400 + s;
        #pragma unroll 4
        for (int k=0;k<64;k++){
          float e = bf2f(pp2[k*400]) + hq_s[k] + c_old*wv_s[k];
          a += tanh_(e)*wv_s[64+k];
        }
        p_val = (p.src_seq[b*400+s] == PAD_ID_C) ? 0.f : __expf(a);
        p_s[s] = p_val;
      }
      red[tid] = (s < 400) ? p_val : 0.f;
      __syncthreads();
      for (int st=256; st>0; st>>=1){ if (tid<st) red[tid]+=red[tid+st]; __syncthreads(); }
      float total = red[0];
      float inv_total = 1.f/total;
      __syncthreads();

      // phase 3: attn, cov update, cov_loss
      float cl = 0.f;
      float inv_t = 1.f/(float)(t < 1 ? 1 : t);
      if (s < 400){
        float attn = p_val*inv_total;
        if (g == 0){
          p.out_copypred[((size_t)b*64 + t)*400 + s] = attn;
          cov_w[b*400+s] = c_old + attn;
          if (t == 63) p.out_attnlast[b*400+s] = attn;
        }
        cl = fminf(attn, c_old*inv_t);
      }
      red[tid] = cl;
      __syncthreads();
      for (int st=256; st>0; st>>=1){ if (tid<st) red[tid]+=red[tid+st]; __syncthreads(); }
      if (g == 0 && tid == 0) p.out_covloss[b*64 + t] = red[0];

      // phase 4: ctx slice (128 d per block, 4-way s-split)
      {
        int d = tid & 127, sp = tid >> 7;
        int dg = g*128 + d;
        float a = 0.f;
        const unsigned short* ep = p.enc_bf + (size_t)(b*400)*512 + dg;
        for (int ss = sp; ss < 400; ss += 4) a += p_s[ss]*bf2f(ep[(size_t)ss*512]);
        cred[sp][d] = a;
      }
      __syncthreads();
      if (tid < 128){
        float cx = (cred[0][tid]+cred[1][tid]+cred[2][tid]+cred[3][tid])*inv_total;
        int dg = g*128 + tid;
        p.ctx_f32[b*512+dg] = cx;
        p.ctx_pk[pkidx(b,dg)] = f2bf(cx);
        if (t == 63) p.out_ctxf[b*512+dg] = cx;
      }
    } else {
      // t == 64: final maxout of readout(63)
      if (g == 0 && tid < 256){
        const int b = b_at;
        float r0 = p.robuf[b*512 + 2*tid]     + p.b_read[2*tid];
        float r1 = p.robuf[b*512 + 2*tid + 1] + p.b_read[2*tid + 1];
        p.out_pred[((size_t)b*64 + 63)*256 + tid] = fmaxf(r0, r1);
      }
    }
    gridbar(p.bar, (++nbar)*128);
  }
}

// ---------------- host ----------------
extern "C" void kernel_launch(void* const* d_in, const int* in_sizes, int n_in,
                              void* d_out, int out_size, void* d_ws, size_t ws_size,
                              hipStream_t stream) {
  const int*   tgt     = (const int*)  d_in[0];
  const int*   src     = (const int*)  d_in[1];
  const float* enc     = (const float*)d_in[2];
  const float* hidden  = (const float*)d_in[3];
  const float* wemb    = (const float*)d_in[4];
  const float* W_init  = (const float*)d_in[5];
  const float* b_init  = (const float*)d_in[6];
  const float* Wx      = (const float*)d_in[7];
  const float* Wh      = (const float*)d_in[8];
  const float* bx      = (const float*)d_in[9];
  const float* bh      = (const float*)d_in[10];
  const float* Wc      = (const float*)d_in[11];
  const float* Wq      = (const float*)d_in[12];
  const float* w_cov   = (const float*)d_in[13];
  const float* v_att   = (const float*)d_in[14];
  const float* W_copy  = (const float*)d_in[15];
  const float* b_copy  = (const float*)d_in[16];
  const float* W_read  = (const float*)d_in[17];
  const float* b_read  = (const float*)d_in[18];

  float* out0 = (float*)d_out;            // pred [32,64,256]
  float* out1 = out0 + 524288;            // attn_last [32,400]
  float* out2 = out0 + 537088;            // ctx_f [32,512]
  float* out3 = out0 + 553472;            // copy_pred [32,64,400]
  float* out4 = out0 + 1372672;           // copy_gate [32,64,1]
  float* out5 = out0 + 1374720;           // coverage_pred [32,64]

  uint8_t* w = (uint8_t*)d_ws;
  unsigned short* emb_pk = (unsigned short*)(w);              // 2,097,152 B
  unsigned short* enc_bf = (unsigned short*)(w + 2097152);    // 13,107,200
  unsigned short* pre_t  = (unsigned short*)(w + 15204352);   // 1,638,400
  unsigned short* wx_pk  = (unsigned short*)(w + 16842752);   // 3,145,728
  unsigned short* wh_pk  = (unsigned short*)(w + 19988480);   // 1,572,864
  unsigned short* wr_pk  = (unsigned short*)(w + 21561344);   // 1,572,864
  unsigned short* wq_bf  = (unsigned short*)(w + 23134208);   // 65,536
  float* gxbuf  = (float*)(w + 23199744);                     // 196,608
  float* ghbuf  = (float*)(w + 23396352);                     // 196,608
  float* robuf  = (float*)(w + 23592960);                     // 65,536
  float* h_f32A = (float*)(w + 23658496);                     // 65,536 (slot 0)
  unsigned short* h_pk   = (unsigned short*)(w + 23724032);   // 32,768
  float* ctx_f32 = (float*)(w + 23756800);                    // 65,536
  unsigned short* ctx_pk = (unsigned short*)(w + 23822336);   // 32,768
  float* covb   = (float*)(w + 23855104);                     // 102,400  (2x ping-pong)
  float* h_f32B = (float*)(w + 23957504);                     // 65,536 (slot 1)
  int*   bar    = (int*)  (w + 24023040);                     // 4 (grid barrier)

  // init
  k_pack<<<768, 256, 0, stream>>>(Wx, wx_pk, 1536, 1024);
  k_pack<<<384, 256, 0, stream>>>(Wh, wh_pk, 1536, 512);
  k_pack<<<384, 256, 0, stream>>>(W_read, wr_pk, 512, 1536);
  k_misc<<<178, 256, 0, stream>>>(Wq, wq_bf, covb);
  k_emb<<<2048, 256, 0, stream>>>(tgt, wemb, emb_pk);
  k_encbf<<<25600, 256, 0, stream>>>(enc, enc_bf);
  k_pre<<<12800, 64, 0, stream>>>(enc, Wc, pre_t);
  k_h0<<<32, 512, 0, stream>>>(hidden, W_init, b_init, h_f32A, h_pk, ctx_f32, ctx_pk, bar);

  // all 64 steps + t=64 tail (readout(63), copy_gate(63), maxout(63)) in one
  // persistent cooperative kernel
  PP p;
  p.emb_pk = emb_pk; p.h_pk = h_pk; p.ctx_pk = ctx_pk;
  p.wx_pk = wx_pk; p.wh_pk = wh_pk; p.wr_pk = wr_pk;
  p.gxbuf = gxbuf; p.ghbuf = ghbuf; p.robuf = robuf;
  p.hA = h_f32A; p.hB = h_f32B; p.ctx_f32 = ctx_f32;
  p.W_copy = W_copy; p.b_copy = b_copy; p.out_gate = out4;
  p.bx = bx; p.bh = bh; p.b_read = b_read;
  p.cov_base = covb;
  p.pre_t = pre_t; p.wq_bf = wq_bf;
  p.w_cov = w_cov; p.v_att = v_att;
  p.enc_bf = enc_bf; p.src_seq = src;
  p.out_pred = out0; p.out_attnlast = out1; p.out_ctxf = out2;
  p.out_copypred = out3; p.out_covloss = out5;
  p.bar = bar;

  void* kargs[] = { (void*)&p };
  hipLaunchCooperativeKernel((const void*)k_steps, dim3(128), dim3(512), kargs, 0, stream);
}

// Round 2
// 7284.979 us; speedup vs baseline: 1.0477x; 1.0477x over previous
//
#include <hip/hip_runtime.h>
#include <cstdint>
#include <cstddef>

// RNNDecoder: B=32, T=64, S=400, V=50257, DW=DM=DE=512, DK=64, POOL=2
// Persistent cooperative kernel (128 blocks x 512 threads), 2 grid barriers/step.
// Round-2 fix: NO device-scope fences (they invalidated L2 every phase ->
// 976 MB refetch, 57us/barrier). Instead, only the mutable inter-block buffers
// (gx/gh/ro, h, ctx, cov) use agent-scope relaxed atomic load/store (sc0 sc1,
// L2-bypass, coherent at L3). Read-only arrays (weights, enc_bf, pre_t, emb_pk)
// use normal cached loads and stay L2/L1-resident across all 64 steps.
// Barrier correctness: __syncthreads() drains vmcnt per wave (sc1 stores reach
// the coherence point) before the leader's relaxed atomic arrive/poll.

#define PAD_ID_C 50256

typedef float f32x4 __attribute__((ext_vector_type(4)));
typedef short bf16x8 __attribute__((ext_vector_type(8)));

__device__ __forceinline__ unsigned short f2bf(float x){
  union { float f; unsigned u; } v; v.f = x;
  unsigned r = (v.u + 0x7FFFu + ((v.u >> 16) & 1u)) >> 16;
  return (unsigned short)r;
}
__device__ __forceinline__ float bf2f(unsigned short h){
  union { unsigned u; float f; } v; v.u = ((unsigned)h) << 16; return v.f;
}
__device__ __forceinline__ float sigm_(float x){ return 1.f/(1.f+__expf(-x)); }
__device__ __forceinline__ float tanh_(float x){ float e=__expf(2.f*x); return 1.f - 2.f/(e+1.f); }

// ---- coherent (L2-bypass) accessors for cross-block mutable data ----
__device__ __forceinline__ float cldf(const float* p){
  return __hip_atomic_load(p, __ATOMIC_RELAXED, __HIP_MEMORY_SCOPE_AGENT);
}
__device__ __forceinline__ void cstf(float* p, float v){
  __hip_atomic_store(p, v, __ATOMIC_RELAXED, __HIP_MEMORY_SCOPE_AGENT);
}
__device__ __forceinline__ void csts(unsigned short* p, unsigned short v){
  __hip_atomic_store(p, v, __ATOMIC_RELAXED, __HIP_MEMORY_SCOPE_AGENT);
}
__device__ __forceinline__ bf16x8 cld8(const unsigned short* p){
  union { unsigned long long u[2]; bf16x8 v; } r;
  const unsigned long long* q = (const unsigned long long*)p;
  r.u[0] = __hip_atomic_load(q,   __ATOMIC_RELAXED, __HIP_MEMORY_SCOPE_AGENT);
  r.u[1] = __hip_atomic_load(q+1, __ATOMIC_RELAXED, __HIP_MEMORY_SCOPE_AGENT);
  return r.v;
}

// packed A-activation index for [32][512] src -> tiles (mt,kt,lane,8)
__device__ __forceinline__ int pkidx(int b, int d){
  return ((((b>>4)*16) + (d>>5))*64 + (((d>>3)&3)*16) + (b&15))*8 + (d&7);
}

// ---------------- init kernels ----------------

__global__ void k_pack(const float* __restrict__ W, unsigned short* __restrict__ pk, int N, int K){
  int ktc = K >> 5;
  int gid = blockIdx.x*256 + threadIdx.x;
  int total = (N>>4)*ktc*64;
  if (gid >= total) return;
  int lane = gid & 63;
  int rem = gid >> 6;
  int kt = rem % ktc, nt = rem / ktc;
  int k0 = kt*32 + (lane>>4)*8;
  int n  = nt*16 + (lane&15);
  #pragma unroll
  for (int j=0;j<8;j++) pk[gid*8+j] = f2bf(W[(k0+j)*N + n]);
}

__global__ void k_misc(const float* __restrict__ Wq, unsigned short* __restrict__ wq_bf,
                       float* __restrict__ cov0){
  int idx = blockIdx.x*256 + threadIdx.x;
  if (idx < 512*64) wq_bf[idx] = f2bf(Wq[idx]);
  else if (idx < 512*64 + 32*400) cov0[idx - 512*64] = 0.f;
}

__global__ void k_emb(const int* __restrict__ tgt, const float* __restrict__ word_emb,
                      unsigned short* __restrict__ emb_pk){
  int bid = blockIdx.x;           // t*32+b
  int t = bid >> 5, b = bid & 31;
  int token = tgt[b*64 + t];
  const float* src = word_emb + (size_t)token*512;
  for (int d = threadIdx.x; d < 512; d += 256){
    int idx = (((t*2 + (b>>4))*16 + (d>>5))*64 + ((d>>3)&3)*16 + (b&15))*8 + (d&7);
    emb_pk[idx] = f2bf(src[d]);
  }
}

__global__ void k_encbf(const float* __restrict__ enc, unsigned short* __restrict__ enc_bf){
  int idx = blockIdx.x*256 + threadIdx.x;
  if (idx < 32*400*512) enc_bf[idx] = f2bf(enc[idx]);
}

// 4-way K-split version (was: 64 threads, 512-deep serial FMA chain, 63us)
__global__ void k_pre(const float* __restrict__ enc, const float* __restrict__ Wc,
                      unsigned short* __restrict__ pre_t){
  __shared__ float part[4][64];
  int bs = blockIdx.x;            // b*400+s
  int b = bs / 400, s = bs % 400;
  int k = threadIdx.x & 63, dp = threadIdx.x >> 6;   // 256 threads
  const float* e = enc + (size_t)bs*512;
  float acc = 0.f;
  for (int d = dp*128; d < dp*128 + 128; d++) acc += e[d]*Wc[d*64+k];
  part[dp][k] = acc;
  __syncthreads();
  if (threadIdx.x < 64){
    float a = part[0][k] + part[1][k] + part[2][k] + part[3][k];
    pre_t[(b*64+k)*400 + s] = f2bf(a);
  }
}

// h0 = tanh(hidden@W_init + b_init); ctx=0; also zero the grid barrier counter
__global__ void k_h0(const float* __restrict__ hidden, const float* __restrict__ W_init,
                     const float* __restrict__ b_init,
                     float* __restrict__ h_f32, unsigned short* __restrict__ h_pk,
                     float* __restrict__ ctx_f32, unsigned short* __restrict__ ctx_pk,
                     int* __restrict__ bar){
  int b = blockIdx.x, jj = threadIdx.x;   // 32 x 512
  if (b == 0 && jj == 0) *bar = 0;
  const float* hv = hidden + b*512;
  float acc = 0.f;
  for (int d=0; d<512; d++) acc += hv[d]*W_init[d*512+jj];
  float h = tanh_(acc + b_init[jj]);
  h_f32[b*512+jj] = h;
  h_pk[pkidx(b,jj)] = f2bf(h);
  ctx_f32[b*512+jj] = 0.f;
  ctx_pk[b*512+jj] = 0;   // zeros in any layout are zeros
}

// ---------------- persistent step kernel ----------------

struct PP {
  const unsigned short* emb_pk;
  unsigned short* h_pk;
  unsigned short* ctx_pk;
  const unsigned short* wx_pk;
  const unsigned short* wh_pk;
  const unsigned short* wr_pk;
  float* gxbuf; float* ghbuf; float* robuf;
  float* hA; float* hB;            // ping-pong h_f32 slots (hA = slot 0, written by k_h0)
  float* ctx_f32;
  const float* W_copy; const float* b_copy;
  float* out_gate;
  const float* bx; const float* bh; const float* b_read;
  float* cov_base;
  const unsigned short* pre_t; const unsigned short* wq_bf;
  const float* w_cov; const float* v_att;
  const unsigned short* enc_bf; const int* src_seq;
  float* out_pred; float* out_attnlast; float* out_ctxf;
  float* out_copypred; float* out_covloss;
  int* bar;
};

// Fence-free grid barrier: no L2 writeback/invalidate. All cross-block data
// moves through sc1 (L2-bypass) accesses; __syncthreads drains each wave's
// vmcnt so those stores are globally visible before arrival. Counter is
// monotonic, zeroed by k_h0 each launch (graph-replay safe).
__device__ __forceinline__ void gridbar(int* bar, int target){
  asm volatile("s_waitcnt vmcnt(0) lgkmcnt(0)" ::: "memory");
  __syncthreads();
  if (threadIdx.x == 0){
    __hip_atomic_fetch_add(bar, 1, __ATOMIC_RELAXED, __HIP_MEMORY_SCOPE_AGENT);
    while (__hip_atomic_load(bar, __ATOMIC_RELAXED, __HIP_MEMORY_SCOPE_AGENT) < target)
      __builtin_amdgcn_s_sleep(4);
  }
  __syncthreads();
}

__global__ __launch_bounds__(512,1) void k_steps(PP p){
  __shared__ float h_s[512];
  __shared__ float hq_part[8][64];
  __shared__ float hq_s[64];
  __shared__ float wv_s[128];
  __shared__ float p_s[400];
  __shared__ float red[512];
  __shared__ float cred[4][128];

  const int tid = threadIdx.x;
  const int b_at = blockIdx.x >> 2, g = blockIdx.x & 3;
  int nbar = 0;

  for (int t = 0; t <= 64; ++t){
    // h ping-pong: hr = h(t-1) (attn(t-1) wrote slot t&1; k_h0 wrote slot 0)
    const float* hr = (t & 1) ? p.hB : p.hA;
    float*       hw = (t & 1) ? p.hA : p.hB;

    // ---------------- GEMM phase ----------------
    {
      int wib  = tid >> 6;               // wave in block, 0..7
      int lane = tid & 63;
      int wv = wib*128 + blockIdx.x;     // block-fixed jobs -> L2/L1-hot weight slices
      if (wib < 4){
        if (wv < 384){
          if (t < 64){
            int isGh = (wv >= 192);
            int ww = isGh ? wv-192 : wv;
            int nt = ww % 96, mt = ww / 96;
            f32x4 acc = {0.f,0.f,0.f,0.f};
            if (!isGh){
              const bf16x8* wp = (const bf16x8*)p.wx_pk + (size_t)(nt*32)*64 + lane;
              const bf16x8* ae = (const bf16x8*)p.emb_pk + (size_t)((t*2+mt)*16)*64 + lane;
              const unsigned short* ac = p.ctx_pk + ((size_t)(mt*16)*64 + lane)*8;
              #pragma unroll
              for (int kt=0; kt<16; kt++)
                acc = __builtin_amdgcn_mfma_f32_16x16x32_bf16(ae[kt*64], wp[kt*64], acc, 0,0,0);
              #pragma unroll
              for (int kt=0; kt<16; kt++)
                acc = __builtin_amdgcn_mfma_f32_16x16x32_bf16(cld8(ac + kt*64*8), wp[(16+kt)*64], acc, 0,0,0);
              int row = mt*16 + (lane>>4)*4, col = nt*16 + (lane&15);
              #pragma unroll
              for (int i=0;i<4;i++) cstf(&p.gxbuf[(row+i)*1536 + col], acc[i]);
            } else {
              const bf16x8* wp = (const bf16x8*)p.wh_pk + (size_t)(nt*16)*64 + lane;
              const unsigned short* ah = p.h_pk + ((size_t)(mt*16)*64 + lane)*8;
              #pragma unroll
              for (int kt=0; kt<16; kt++)
                acc = __builtin_amdgcn_mfma_f32_16x16x32_bf16(cld8(ah + kt*64*8), wp[kt*64], acc, 0,0,0);
              int row = mt*16 + (lane>>4)*4, col = nt*16 + (lane&15);
              #pragma unroll
              for (int i=0;i<4;i++) cstf(&p.ghbuf[(row+i)*1536 + col], acc[i]);
            }
          }
        } else if (wv < 448){
          if (t > 0){
            int i = wv - 384;
            int nt = i % 32, mt = i / 32;
            f32x4 acc = {0.f,0.f,0.f,0.f};
            const bf16x8* wp = (const bf16x8*)p.wr_pk + (size_t)(nt*48)*64 + lane;
            const bf16x8* ae = (const bf16x8*)p.emb_pk + (size_t)(((t-1)*2+mt)*16)*64 + lane;
            const unsigned short* ah = p.h_pk + ((size_t)(mt*16)*64 + lane)*8;
            const unsigned short* ac = p.ctx_pk + ((size_t)(mt*16)*64 + lane)*8;
            #pragma unroll
            for (int kt=0; kt<16; kt++)
              acc = __builtin_amdgcn_mfma_f32_16x16x32_bf16(ae[kt*64], wp[kt*64], acc, 0,0,0);
            #pragma unroll
            for (int kt=0; kt<16; kt++)
              acc = __builtin_amdgcn_mfma_f32_16x16x32_bf16(cld8(ah + kt*64*8), wp[(16+kt)*64], acc, 0,0,0);
            #pragma unroll
            for (int kt=0; kt<16; kt++)
              acc = __builtin_amdgcn_mfma_f32_16x16x32_bf16(cld8(ac + kt*64*8), wp[(32+kt)*64], acc, 0,0,0);
            int row = mt*16 + (lane>>4)*4, col = nt*16 + (lane&15);
            #pragma unroll
            for (int i=0;i<4;i++) cstf(&p.robuf[(row+i)*512 + col], acc[i]);
          }
        } else if (wv < 480){
          if (t > 0){
            int b = wv - 448;   // copy_gate(t-1) = sigmoid([h(t-1),ctx(t-1)]@W_copy + b_copy)
            float acc = 0.f;
            #pragma unroll
            for (int i=0;i<16;i++){
              int j = i*64 + lane;
              float x = (j < 512) ? cldf(&hr[b*512+j]) : cldf(&p.ctx_f32[b*512 + (j-512)]);
              acc += x * p.W_copy[j];
            }
            for (int off=32; off>0; off>>=1) acc += __shfl_down(acc, off, 64);
            if (lane == 0) p.out_gate[b*64 + (t-1)] = sigm_(acc + p.b_copy[0]);
          }
        }
      }
    }
    gridbar(p.bar, (++nbar)*128);

    // ---------------- ATTN phase ----------------
    if (t < 64){
      const float* cov_r = p.cov_base + (t & 1)*12800;
      float* cov_w = p.cov_base + ((t+1) & 1)*12800;
      const int b = b_at;

      // phase 0: GRU combine -> h(t)
      {
        int jj = tid;
        float gx0 = cldf(&p.gxbuf[b*1536+jj]), gx1 = cldf(&p.gxbuf[b*1536+512+jj]), gx2 = cldf(&p.gxbuf[b*1536+1024+jj]);
        float gh0 = cldf(&p.ghbuf[b*1536+jj]), gh1 = cldf(&p.ghbuf[b*1536+512+jj]), gh2 = cldf(&p.ghbuf[b*1536+1024+jj]);
        float r = sigm_(gx0 + p.bx[jj]     + gh0 + p.bh[jj]);
        float z = sigm_(gx1 + p.bx[512+jj] + gh1 + p.bh[512+jj]);
        float n = tanh_(gx2 + p.bx[1024+jj] + r*(gh2 + p.bh[1024+jj]));
        float hold = cldf(&hr[b*512+jj]);
        float hn = (1.f - z)*n + z*hold;
        h_s[jj] = hn;
        if (g == 0){ cstf(&hw[b*512+jj], hn); csts(&p.h_pk[pkidx(b,jj)], f2bf(hn)); }
      }
      if (tid < 128) wv_s[tid] = (tid < 64) ? p.w_cov[tid] : p.v_att[tid-64];
      // phase 0b: maxout of readout(t-1)
      if (t > 0 && g == 0 && tid < 256){
        float r0 = cldf(&p.robuf[b*512 + 2*tid])     + p.b_read[2*tid];
        float r1 = cldf(&p.robuf[b*512 + 2*tid + 1]) + p.b_read[2*tid + 1];
        p.out_pred[((size_t)b*64 + (t-1))*256 + tid] = fmaxf(r0, r1);
      }
      __syncthreads();

      // phase 1: hq = h @ Wq  (64 outputs, 8-way k-split)
      {
        int k = tid & 63, pr = tid >> 6;
        float a = 0.f;
        const unsigned short* wq = p.wq_bf + k;
        for (int d = pr*64; d < pr*64 + 64; d++) a += h_s[d]*bf2f(wq[d*64]);
        hq_part[pr][k] = a;
      }
      __syncthreads();
      if (tid < 64){
        float a = 0.f;
        #pragma unroll
        for (int pr=0;pr<8;pr++) a += hq_part[pr][tid];
        hq_s[tid] = a;
      }
      __syncthreads();

      // phase 2: scores + exp (no max-subtraction: |score| < ~1)
      float c_old = 0.f, p_val = 0.f;
      int s = tid;
      if (s < 400){
        c_old = cldf(&cov_r[b*400+s]);
        float a = 0.f;
        const unsigned short* pp2 = p.pre_t + (b*64)*400 + s;
        #pragma unroll 4
        for (int k=0;k<64;k++){
          float e = bf2f(pp2[k*400]) + hq_s[k] + c_old*wv_s[k];
          a += tanh_(e)*wv_s[64+k];
        }
        p_val = (p.src_seq[b*400+s] == PAD_ID_C) ? 0.f : __expf(a);
        p_s[s] = p_val;
      }
      red[tid] = (s < 400) ? p_val : 0.f;
      __syncthreads();
      for (int st=256; st>0; st>>=1){ if (tid<st) red[tid]+=red[tid+st]; __syncthreads(); }
      float total = red[0];
      float inv_total = 1.f/total;
      __syncthreads();

      // phase 3: attn, cov update, cov_loss
      float cl = 0.f;
      float inv_t = 1.f/(float)(t < 1 ? 1 : t);
      if (s < 400){
        float attn = p_val*inv_total;
        if (g == 0){
          p.out_copypred[((size_t)b*64 + t)*400 + s] = attn;
          cstf(&cov_w[b*400+s], c_old + attn);
          if (t == 63) p.out_attnlast[b*400+s] = attn;
        }
        cl = fminf(attn, c_old*inv_t);
      }
      red[tid] = cl;
      __syncthreads();
      for (int st=256; st>0; st>>=1){ if (tid<st) red[tid]+=red[tid+st]; __syncthreads(); }
      if (g == 0 && tid == 0) p.out_covloss[b*64 + t] = red[0];

      // phase 4: ctx slice (128 d per block, 4-way s-split)
      {
        int d = tid & 127, sp = tid >> 7;
        int dg = g*128 + d;
        float a = 0.f;
        const unsigned short* ep = p.enc_bf + (size_t)(b*400)*512 + dg;
        for (int ss = sp; ss < 400; ss += 4) a += p_s[ss]*bf2f(ep[(size_t)ss*512]);
        cred[sp][d] = a;
      }
      __syncthreads();
      if (tid < 128){
        float cx = (cred[0][tid]+cred[1][tid]+cred[2][tid]+cred[3][tid])*inv_total;
        int dg = g*128 + tid;
        cstf(&p.ctx_f32[b*512+dg], cx);
        csts(&p.ctx_pk[pkidx(b,dg)], f2bf(cx));
        if (t == 63) p.out_ctxf[b*512+dg] = cx;
      }
    } else {
      // t == 64: final maxout of readout(63)
      if (g == 0 && tid < 256){
        const int b = b_at;
        float r0 = cldf(&p.robuf[b*512 + 2*tid])     + p.b_read[2*tid];
        float r1 = cldf(&p.robuf[b*512 + 2*tid + 1]) + p.b_read[2*tid + 1];
        p.out_pred[((size_t)b*64 + 63)*256 + tid] = fmaxf(r0, r1);
      }
    }
    gridbar(p.bar, (++nbar)*128);
  }
}

// ---------------- host ----------------
extern "C" void kernel_launch(void* const* d_in, const int* in_sizes, int n_in,
                              void* d_out, int out_size, void* d_ws, size_t ws_size,
                              hipStream_t stream) {
  const int*   tgt     = (const int*)  d_in[0];
  const int*   src     = (const int*)  d_in[1];
  const float* enc     = (const float*)d_in[2];
  const float* hidden  = (const float*)d_in[3];
  const float* wemb    = (const float*)d_in[4];
  const float* W_init  = (const float*)d_in[5];
  const float* b_init  = (const float*)d_in[6];
  const float* Wx      = (const float*)d_in[7];
  const float* Wh      = (const float*)d_in[8];
  const float* bx      = (const float*)d_in[9];
  const float* bh      = (const float*)d_in[10];
  const float* Wc      = (const float*)d_in[11];
  const float* Wq      = (const float*)d_in[12];
  const float* w_cov   = (const float*)d_in[13];
  const float* v_att   = (const float*)d_in[14];
  const float* W_copy  = (const float*)d_in[15];
  const float* b_copy  = (const float*)d_in[16];
  const float* W_read  = (const float*)d_in[17];
  const float* b_read  = (const float*)d_in[18];

  float* out0 = (float*)d_out;            // pred [32,64,256]
  float* out1 = out0 + 524288;            // attn_last [32,400]
  float* out2 = out0 + 537088;            // ctx_f [32,512]
  float* out3 = out0 + 553472;            // copy_pred [32,64,400]
  float* out4 = out0 + 1372672;           // copy_gate [32,64,1]
  float* out5 = out0 + 1374720;           // coverage_pred [32,64]

  uint8_t* w = (uint8_t*)d_ws;
  unsigned short* emb_pk = (unsigned short*)(w);              // 2,097,152 B
  unsigned short* enc_bf = (unsigned short*)(w + 2097152);    // 13,107,200
  unsigned short* pre_t  = (unsigned short*)(w + 15204352);   // 1,638,400
  unsigned short* wx_pk  = (unsigned short*)(w + 16842752);   // 3,145,728
  unsigned short* wh_pk  = (unsigned short*)(w + 19988480);   // 1,572,864
  unsigned short* wr_pk  = (unsigned short*)(w + 21561344);   // 1,572,864
  unsigned short* wq_bf  = (unsigned short*)(w + 23134208);   // 65,536
  float* gxbuf  = (float*)(w + 23199744);                     // 196,608
  float* ghbuf  = (float*)(w + 23396352);                     // 196,608
  float* robuf  = (float*)(w + 23592960);                     // 65,536
  float* h_f32A = (float*)(w + 23658496);                     // 65,536 (slot 0)
  unsigned short* h_pk   = (unsigned short*)(w + 23724032);   // 32,768
  float* ctx_f32 = (float*)(w + 23756800);                    // 65,536
  unsigned short* ctx_pk = (unsigned short*)(w + 23822336);   // 32,768
  float* covb   = (float*)(w + 23855104);                     // 102,400  (2x ping-pong)
  float* h_f32B = (float*)(w + 23957504);                     // 65,536 (slot 1)
  int*   bar    = (int*)  (w + 24023040);                     // 4 (grid barrier)

  // init
  k_pack<<<768, 256, 0, stream>>>(Wx, wx_pk, 1536, 1024);
  k_pack<<<384, 256, 0, stream>>>(Wh, wh_pk, 1536, 512);
  k_pack<<<384, 256, 0, stream>>>(W_read, wr_pk, 512, 1536);
  k_misc<<<178, 256, 0, stream>>>(Wq, wq_bf, covb);
  k_emb<<<2048, 256, 0, stream>>>(tgt, wemb, emb_pk);
  k_encbf<<<25600, 256, 0, stream>>>(enc, enc_bf);
  k_pre<<<12800, 256, 0, stream>>>(enc, Wc, pre_t);
  k_h0<<<32, 512, 0, stream>>>(hidden, W_init, b_init, h_f32A, h_pk, ctx_f32, ctx_pk, bar);

  // all 64 steps + t=64 tail in one persistent cooperative kernel
  PP p;
  p.emb_pk = emb_pk; p.h_pk = h_pk; p.ctx_pk = ctx_pk;
  p.wx_pk = wx_pk; p.wh_pk = wh_pk; p.wr_pk = wr_pk;
  p.gxbuf = gxbuf; p.ghbuf = ghbuf; p.robuf = robuf;
  p.hA = h_f32A; p.hB = h_f32B; p.ctx_f32 = ctx_f32;
  p.W_copy = W_copy; p.b_copy = b_copy; p.out_gate = out4;
  p.bx = bx; p.bh = bh; p.b_read = b_read;
  p.cov_base = covb;
  p.pre_t = pre_t; p.wq_bf = wq_bf;
  p.w_cov = w_cov; p.v_att = v_att;
  p.enc_bf = enc_bf; p.src_seq = src;
  p.out_pred = out0; p.out_attnlast = out1; p.out_ctxf = out2;
  p.out_copypred = out3; p.out_covloss = out5;
  p.bar = bar;

  void* kargs[] = { (void*)&p };
  hipLaunchCooperativeKernel((const void*)k_steps, dim3(128), dim3(512), kargs, 0, stream);
}

// Round 3
// 2556.772 us; speedup vs baseline: 2.9852x; 2.8493x over previous
//
#include <hip/hip_runtime.h>
#include <cstdint>
#include <cstddef>

// RNNDecoder: B=32, T=64, S=400, V=50257, DW=DM=DE=512, DK=64, POOL=2
// Persistent cooperative kernel, 256 blocks x 512 threads, 2 barriers/step.
// Round-3: all cross-block mutable state goes to STEP-UNIQUE addresses
// (sc1 write-through stores); consumers use normal CACHED loads (virgin
// address -> guaranteed-fresh IC fill, then L2-shared). No fences, no
// uncached reads, no atomic RMW contention. cov lives in registers.

#define PAD_ID_C 50256

typedef float f32x4 __attribute__((ext_vector_type(4)));
typedef short bf16x8 __attribute__((ext_vector_type(8)));

__device__ __forceinline__ unsigned short f2bf(float x){
  union { float f; unsigned u; } v; v.f = x;
  unsigned r = (v.u + 0x7FFFu + ((v.u >> 16) & 1u)) >> 16;
  return (unsigned short)r;
}
__device__ __forceinline__ float bf2f(unsigned short h){
  union { unsigned u; float f; } v; v.u = ((unsigned)h) << 16; return v.f;
}
__device__ __forceinline__ float sigm_(float x){ return 1.f/(1.f+__expf(-x)); }
__device__ __forceinline__ float tanh_(float x){ float e=__expf(2.f*x); return 1.f - 2.f/(e+1.f); }

// sc1 write-through stores (bypass L2, land at IC) for cross-block data
__device__ __forceinline__ void cstf(float* p, float v){
  __hip_atomic_store(p, v, __ATOMIC_RELAXED, __HIP_MEMORY_SCOPE_AGENT);
}
__device__ __forceinline__ void csts(unsigned short* p, unsigned short v){
  __hip_atomic_store(p, v, __ATOMIC_RELAXED, __HIP_MEMORY_SCOPE_AGENT);
}

// packed A-activation index for [32][512] src -> tiles (mt,kt,lane,8)
__device__ __forceinline__ int pkidx(int b, int d){
  return ((((b>>4)*16) + (d>>5))*64 + (((d>>3)&3)*16) + (b&15))*8 + (d&7);
}

// ---------------- init kernels ----------------

__global__ void k_pack(const float* __restrict__ W, unsigned short* __restrict__ pk, int N, int K){
  int ktc = K >> 5;
  int gid = blockIdx.x*256 + threadIdx.x;
  int total = (N>>4)*ktc*64;
  if (gid >= total) return;
  int lane = gid & 63;
  int rem = gid >> 6;
  int kt = rem % ktc, nt = rem / ktc;
  int k0 = kt*32 + (lane>>4)*8;
  int n  = nt*16 + (lane&15);
  #pragma unroll
  for (int j=0;j<8;j++) pk[gid*8+j] = f2bf(W[(k0+j)*N + n]);
}

// wq transposed to [k][d] + zero the barrier region
__global__ void k_misc(const float* __restrict__ Wq, unsigned short* __restrict__ wq_t,
                       int* __restrict__ barz){
  int idx = blockIdx.x*256 + threadIdx.x;
  if (idx < 32768){ int k = idx >> 9, d = idx & 511; wq_t[idx] = f2bf(Wq[d*64+k]); }
  else if (idx < 32768 + 4112) barz[idx - 32768] = 0;
}

__global__ void k_emb(const int* __restrict__ tgt, const float* __restrict__ word_emb,
                      unsigned short* __restrict__ emb_pk){
  int bid = blockIdx.x;           // t*32+b
  int t = bid >> 5, b = bid & 31;
  int token = tgt[b*64 + t];
  const float* src = word_emb + (size_t)token*512;
  for (int d = threadIdx.x; d < 512; d += 256){
    int idx = (((t*2 + (b>>4))*16 + (d>>5))*64 + ((d>>3)&3)*16 + (b&15))*8 + (d&7);
    emb_pk[idx] = f2bf(src[d]);
  }
}

__global__ void k_encbf(const float* __restrict__ enc, unsigned short* __restrict__ enc_bf){
  int idx = blockIdx.x*256 + threadIdx.x;
  if (idx < 32*400*512) enc_bf[idx] = f2bf(enc[idx]);
}

// pre_t transposed to [b][s][64]: contiguous 128B per (b,s) row
__global__ void k_pre(const float* __restrict__ enc, const float* __restrict__ Wc,
                      unsigned short* __restrict__ pre_t){
  __shared__ float part[4][64];
  int bs = blockIdx.x;            // b*400+s
  int k = threadIdx.x & 63, dp = threadIdx.x >> 6;   // 256 threads
  const float* e = enc + (size_t)bs*512;
  float acc = 0.f;
  for (int d = dp*128; d < dp*128 + 128; d++) acc += e[d]*Wc[d*64+k];
  part[dp][k] = acc;
  __syncthreads();
  if (threadIdx.x < 64){
    float a = part[0][k] + part[1][k] + part[2][k] + part[3][k];
    pre_t[(size_t)bs*64 + k] = f2bf(a);
  }
}

// h0 = tanh(hidden@W_init + b_init) into slot-0 state arrays; ctx0 = 0
__global__ void k_h0(const float* __restrict__ hidden, const float* __restrict__ W_init,
                     const float* __restrict__ b_init,
                     float* __restrict__ hf0, unsigned short* __restrict__ hpk0,
                     float* __restrict__ cf0, unsigned short* __restrict__ cpk0){
  int b = blockIdx.x, jj = threadIdx.x;   // 32 x 512
  const float* hv = hidden + b*512;
  float acc = 0.f;
  for (int d=0; d<512; d++) acc += hv[d]*W_init[d*512+jj];
  float h = tanh_(acc + b_init[jj]);
  hf0[b*512+jj] = h;
  hpk0[pkidx(b,jj)] = f2bf(h);
  cf0[b*512+jj] = 0.f;
  cpk0[b*512+jj] = 0;   // zeros in any layout are zeros
}

// ---------------- persistent step kernel ----------------

struct PP {
  const unsigned short *emb, *wx, *wh, *wr, *wq, *pre, *enc;
  unsigned short *hpk, *cpk;                // 65 slots x 16384 shorts
  float *gx, *gh;                           // 64 slots x 49152 floats
  float *ro;                                // 65 slots x 16384 floats
  float *hf, *cf;                           // 65 slots x 16384 floats
  const float *Wcopy, *bcopy, *bx, *bh, *bread, *wcov, *vatt;
  const int* src;
  float *out_pred, *out_attnlast, *out_ctxf, *out_copypred, *out_gate, *out_covloss;
  int *arr;     // 256 x 16 ints (one cacheline per block)
  int *flag;    // release flag
};

// Contention-free barrier: per-block arrival line + master gather + release flag.
// No RMW; all sc1. Entry waitcnt drains each wave's sc1 data stores first.
__device__ __forceinline__ void gridbar(int* arr, int* flag, int idx){
  asm volatile("s_waitcnt vmcnt(0) lgkmcnt(0)" ::: "memory");
  __syncthreads();
  int tid = threadIdx.x;
  if (blockIdx.x == 0){
    if (tid > 0 && tid < 256){
      while (__hip_atomic_load(arr + tid*16, __ATOMIC_RELAXED, __HIP_MEMORY_SCOPE_AGENT) < idx)
        __builtin_amdgcn_s_sleep(1);
    }
    __syncthreads();
    if (tid == 0)
      __hip_atomic_store(flag, idx, __ATOMIC_RELAXED, __HIP_MEMORY_SCOPE_AGENT);
  } else {
    if (tid == 0){
      __hip_atomic_store(arr + blockIdx.x*16, idx, __ATOMIC_RELAXED, __HIP_MEMORY_SCOPE_AGENT);
      while (__hip_atomic_load(flag, __ATOMIC_RELAXED, __HIP_MEMORY_SCOPE_AGENT) < idx)
        __builtin_amdgcn_s_sleep(2);
    }
  }
  __syncthreads();
}

__device__ __forceinline__ float blockReduceSum(float v, float* redw, int tid){
  #pragma unroll
  for (int off=32; off; off>>=1) v += __shfl_down(v, off, 64);
  if ((tid & 63) == 0) redw[tid>>6] = v;
  __syncthreads();
  if (tid == 0){
    float r = 0.f;
    #pragma unroll
    for (int i=0;i<8;i++) r += redw[i];
    redw[8] = r;
  }
  __syncthreads();
  return redw[8];
}

__global__ __launch_bounds__(512,1) void k_steps(PP p){
  __shared__ float h_s[512];
  __shared__ float hq_part[8][64];
  __shared__ float hq_s[64];
  __shared__ float wv_s[128];
  __shared__ float p_s[400];
  __shared__ float redw[16];
  __shared__ float cred[64][68];   // padded: bank-safe

  const int tid = threadIdx.x;
  const int b = blockIdx.x & 31, g = blockIdx.x >> 5;   // 8 g-blocks of b on one XCD
  int idx = 0;
  float c_reg = 0.f;               // coverage for s=tid (replicated per g-block)

  if (tid < 128) wv_s[tid] = (tid < 64) ? p.wcov[tid] : p.vatt[tid-64];
  __syncthreads();

  for (int t = 0; t <= 64; ++t){
    // state version t (h(t-1), ctx(t-1)); slot t outputs of this step's GEMM
    const unsigned short* hpk_t = p.hpk + (size_t)t*16384;
    const unsigned short* cpk_t = p.cpk + (size_t)t*16384;
    const float* hf_t = p.hf + (size_t)t*16384;
    const float* cf_t = p.cf + (size_t)t*16384;
    int tg = (t < 64) ? t : 0;     // guard (gx/gh unused at t==64)
    float* gx_t = p.gx + (size_t)tg*49152;
    float* gh_t = p.gh + (size_t)tg*49152;
    float* ro_t = p.ro + (size_t)t*16384;

    // ---------------- GEMM phase: waves 0,1 of every block ----------------
    {
      int wib = tid >> 6, lane = tid & 63;
      if (wib < 2){
        int wv = wib*256 + blockIdx.x;
        if (wv < 192){
          if (t < 64){  // gx = [emb(t)|ctx(t-1)] @ Wx
            int nt = wv % 96, mt = wv / 96;
            f32x4 acc = {0.f,0.f,0.f,0.f};
            const bf16x8* wp = (const bf16x8*)p.wx + (size_t)(nt*32)*64 + lane;
            const bf16x8* ae = (const bf16x8*)p.emb + (size_t)((t*2+mt)*16)*64 + lane;
            const bf16x8* ac = (const bf16x8*)cpk_t + (size_t)(mt*16)*64 + lane;
            #pragma unroll
            for (int kt=0; kt<16; kt++)
              acc = __builtin_amdgcn_mfma_f32_16x16x32_bf16(ae[kt*64], wp[kt*64], acc, 0,0,0);
            #pragma unroll
            for (int kt=0; kt<16; kt++)
              acc = __builtin_amdgcn_mfma_f32_16x16x32_bf16(ac[kt*64], wp[(16+kt)*64], acc, 0,0,0);
            int row = mt*16 + (lane>>4)*4, col = nt*16 + (lane&15);
            #pragma unroll
            for (int i=0;i<4;i++) cstf(&gx_t[(row+i)*1536 + col], acc[i]);
          }
        } else if (wv < 384){
          if (t < 64){  // gh = h(t-1) @ Wh
            int ww = wv - 192;
            int nt = ww % 96, mt = ww / 96;
            f32x4 acc = {0.f,0.f,0.f,0.f};
            const bf16x8* wp = (const bf16x8*)p.wh + (size_t)(nt*16)*64 + lane;
            const bf16x8* ah = (const bf16x8*)hpk_t + (size_t)(mt*16)*64 + lane;
            #pragma unroll
            for (int kt=0; kt<16; kt++)
              acc = __builtin_amdgcn_mfma_f32_16x16x32_bf16(ah[kt*64], wp[kt*64], acc, 0,0,0);
            int row = mt*16 + (lane>>4)*4, col = nt*16 + (lane&15);
            #pragma unroll
            for (int i=0;i<4;i++) cstf(&gh_t[(row+i)*1536 + col], acc[i]);
          }
        } else if (wv < 448){
          if (t > 0){   // readout(t-1) = [emb(t-1)|h(t-1)|ctx(t-1)] @ W_read
            int i = wv - 384;
            int nt = i % 32, mt = i / 32;
            f32x4 acc = {0.f,0.f,0.f,0.f};
            const bf16x8* wp = (const bf16x8*)p.wr + (size_t)(nt*48)*64 + lane;
            const bf16x8* ae = (const bf16x8*)p.emb + (size_t)(((t-1)*2+mt)*16)*64 + lane;
            const bf16x8* ah = (const bf16x8*)hpk_t + (size_t)(mt*16)*64 + lane;
            const bf16x8* ac = (const bf16x8*)cpk_t + (size_t)(mt*16)*64 + lane;
            #pragma unroll
            for (int kt=0; kt<16; kt++)
              acc = __builtin_amdgcn_mfma_f32_16x16x32_bf16(ae[kt*64], wp[kt*64], acc, 0,0,0);
            #pragma unroll
            for (int kt=0; kt<16; kt++)
              acc = __builtin_amdgcn_mfma_f32_16x16x32_bf16(ah[kt*64], wp[(16+kt)*64], acc, 0,0,0);
            #pragma unroll
            for (int kt=0; kt<16; kt++)
              acc = __builtin_amdgcn_mfma_f32_16x16x32_bf16(ac[kt*64], wp[(32+kt)*64], acc, 0,0,0);
            int row = mt*16 + (lane>>4)*4, col = nt*16 + (lane&15);
            #pragma unroll
            for (int i=0;i<4;i++) cstf(&ro_t[(row+i)*512 + col], acc[i]);
          }
        } else if (wv < 480){
          if (t > 0){   // copy_gate(t-1) = sigmoid([h(t-1),ctx(t-1)] @ W_copy + b)
            int b2 = wv - 448;
            float acc = 0.f;
            #pragma unroll
            for (int i=0;i<16;i++){
              int j = i*64 + lane;
              float x = (j < 512) ? hf_t[b2*512+j] : cf_t[b2*512 + (j-512)];
              acc += x * p.Wcopy[j];
            }
            #pragma unroll
            for (int off=32; off>0; off>>=1) acc += __shfl_down(acc, off, 64);
            if (lane == 0) p.out_gate[b2*64 + (t-1)] = sigm_(acc + p.bcopy[0]);
          }
        }
      }
    }
    gridbar(p.arr, p.flag, ++idx);

    // ---------------- ATTN phase ----------------
    if (t < 64){
      float* hf_w = p.hf + (size_t)(t+1)*16384;
      unsigned short* hpk_w = p.hpk + (size_t)(t+1)*16384;
      float* cf_w = p.cf + (size_t)(t+1)*16384;
      unsigned short* cpk_w = p.cpk + (size_t)(t+1)*16384;

      // phase 0: GRU combine -> h(t)   (replicated across g; only g==0 stores)
      {
        int jj = tid;
        const float* gxr = gx_t + b*1536;
        const float* ghr = gh_t + b*1536;
        float gx0 = gxr[jj], gx1 = gxr[512+jj], gx2 = gxr[1024+jj];
        float gh0 = ghr[jj], gh1 = ghr[512+jj], gh2 = ghr[1024+jj];
        float r = sigm_(gx0 + p.bx[jj]      + gh0 + p.bh[jj]);
        float z = sigm_(gx1 + p.bx[512+jj]  + gh1 + p.bh[512+jj]);
        float n = tanh_(gx2 + p.bx[1024+jj] + r*(gh2 + p.bh[1024+jj]));
        float hold = hf_t[b*512+jj];
        float hn = (1.f - z)*n + z*hold;
        h_s[jj] = hn;
        if (g == 0){ cstf(&hf_w[b*512+jj], hn); csts(&hpk_w[pkidx(b,jj)], f2bf(hn)); }
      }
      // phase 0b: maxout of readout(t-1)
      if (t > 0 && g == 0 && tid < 256){
        float r0 = ro_t[b*512 + 2*tid]     + p.bread[2*tid];
        float r1 = ro_t[b*512 + 2*tid + 1] + p.bread[2*tid + 1];
        p.out_pred[((size_t)b*64 + (t-1))*256 + tid] = fmaxf(r0, r1);
      }
      __syncthreads();

      // phase 1: hq = h @ Wq (transposed wq: contiguous per-thread rows)
      {
        int k = tid & 63, pr = tid >> 6;
        const unsigned short* wrow = p.wq + k*512 + pr*64;
        float a = 0.f;
        #pragma unroll
        for (int c=0;c<8;c++){
          bf16x8 v = *(const bf16x8*)(wrow + c*8);
          #pragma unroll
          for (int j=0;j<8;j++) a += h_s[pr*64 + c*8 + j]*bf2f((unsigned short)v[j]);
        }
        hq_part[pr][k] = a;
      }
      __syncthreads();
      if (tid < 64){
        float a = 0.f;
        #pragma unroll
        for (int pr=0;pr<8;pr++) a += hq_part[pr][tid];
        hq_s[tid] = a;
      }
      __syncthreads();

      // phase 2: scores + exp (cov from register; pre row = one 128B line)
      float c_old = c_reg, p_val = 0.f;
      if (tid < 400){
        const unsigned short* prow = p.pre + ((size_t)b*400 + tid)*64;
        float a = 0.f;
        #pragma unroll
        for (int kk=0; kk<8; kk++){
          bf16x8 v = *(const bf16x8*)(prow + kk*8);
          #pragma unroll
          for (int j=0;j<8;j++){
            int k = kk*8 + j;
            float e = bf2f((unsigned short)v[j]) + hq_s[k] + c_old*wv_s[k];
            a += tanh_(e)*wv_s[64+k];
          }
        }
        p_val = (p.src[b*400+tid] == PAD_ID_C) ? 0.f : __expf(a);
        p_s[tid] = p_val;
      }
      float total = blockReduceSum((tid < 400) ? p_val : 0.f, redw, tid);
      float inv_total = 1.f/total;

      // phase 3: attn, cov (register) update, cov_loss
      float cl = 0.f;
      float inv_t = 1.f/(float)(t < 1 ? 1 : t);
      if (tid < 400){
        float attnv = p_val*inv_total;
        if (g == 0){
          p.out_copypred[((size_t)b*64 + t)*400 + tid] = attnv;
          if (t == 63) p.out_attnlast[b*400+tid] = attnv;
        }
        cl = fminf(attnv, c_old*inv_t);
        c_reg = c_old + attnv;
      }
      float cls = blockReduceSum(cl, redw, tid);
      if (g == 0 && tid == 0) p.out_covloss[b*64 + t] = cls;

      // phase 4: ctx slice (this block: 64 d), vectorized 16B loads
      {
        int dv = tid & 7, sp = tid >> 3;      // 8 d-groups x 64 s-splits
        int dgb = g*64 + dv*8;
        float acc[8] = {0.f,0.f,0.f,0.f,0.f,0.f,0.f,0.f};
        const unsigned short* ebase = p.enc + (size_t)(b*400)*512 + dgb;
        for (int ss = sp; ss < 400; ss += 64){
          bf16x8 v = *(const bf16x8*)(ebase + (size_t)ss*512);
          float pw = p_s[ss];
          #pragma unroll
          for (int j=0;j<8;j++) acc[j] += pw*bf2f((unsigned short)v[j]);
        }
        #pragma unroll
        for (int j=0;j<8;j++) cred[sp][dv*8+j] = acc[j];
      }
      __syncthreads();
      if (tid < 64){
        float cx = 0.f;
        #pragma unroll
        for (int s2=0;s2<64;s2++) cx += cred[s2][tid];
        cx *= inv_total;
        int dg = g*64 + tid;
        cstf(&cf_w[b*512+dg], cx);
        csts(&cpk_w[pkidx(b,dg)], f2bf(cx));
        if (t == 63) p.out_ctxf[b*512+dg] = cx;
      }
    } else {
      // t == 64: final maxout of readout(63)
      if (g == 0 && tid < 256){
        float r0 = ro_t[b*512 + 2*tid]     + p.bread[2*tid];
        float r1 = ro_t[b*512 + 2*tid + 1] + p.bread[2*tid + 1];
        p.out_pred[((size_t)b*64 + 63)*256 + tid] = fmaxf(r0, r1);
      }
    }
    gridbar(p.arr, p.flag, ++idx);
  }
}

// ---------------- host ----------------
extern "C" void kernel_launch(void* const* d_in, const int* in_sizes, int n_in,
                              void* d_out, int out_size, void* d_ws, size_t ws_size,
                              hipStream_t stream) {
  const int*   tgt     = (const int*)  d_in[0];
  const int*   src     = (const int*)  d_in[1];
  const float* enc     = (const float*)d_in[2];
  const float* hidden  = (const float*)d_in[3];
  const float* wemb    = (const float*)d_in[4];
  const float* W_init  = (const float*)d_in[5];
  const float* b_init  = (const float*)d_in[6];
  const float* Wx      = (const float*)d_in[7];
  const float* Wh      = (const float*)d_in[8];
  const float* bx      = (const float*)d_in[9];
  const float* bh      = (const float*)d_in[10];
  const float* Wc      = (const float*)d_in[11];
  const float* Wq      = (const float*)d_in[12];
  const float* w_cov   = (const float*)d_in[13];
  const float* v_att   = (const float*)d_in[14];
  const float* W_copy  = (const float*)d_in[15];
  const float* b_copy  = (const float*)d_in[16];
  const float* W_read  = (const float*)d_in[17];
  const float* b_read  = (const float*)d_in[18];

  float* out0 = (float*)d_out;            // pred [32,64,256]
  float* out1 = out0 + 524288;            // attn_last [32,400]
  float* out2 = out0 + 537088;            // ctx_f [32,512]
  float* out3 = out0 + 553472;            // copy_pred [32,64,400]
  float* out4 = out0 + 1372672;           // copy_gate [32,64,1]
  float* out5 = out0 + 1374720;           // coverage_pred [32,64]

  uint8_t* w = (uint8_t*)d_ws;
  unsigned short* emb_pk = (unsigned short*)(w);              // 2,097,152 B
  unsigned short* enc_bf = (unsigned short*)(w + 2097152);    // 13,107,200
  unsigned short* pre_t  = (unsigned short*)(w + 15204352);   // 1,638,400 ([b][s][64])
  unsigned short* wx_pk  = (unsigned short*)(w + 16842752);   // 3,145,728
  unsigned short* wh_pk  = (unsigned short*)(w + 19988480);   // 1,572,864
  unsigned short* wr_pk  = (unsigned short*)(w + 21561344);   // 1,572,864
  unsigned short* wq_t   = (unsigned short*)(w + 23134208);   // 65,536 ([k][d])
  float* gx_sl  = (float*)(w + 23199744);                     // 64 x 196,608 = 12,582,912
  float* gh_sl  = (float*)(w + 35782656);                     // 12,582,912
  float* ro_sl  = (float*)(w + 48365568);                     // 65 x 65,536 = 4,259,840
  unsigned short* hpk_sl = (unsigned short*)(w + 52625408);   // 65 x 32,768 = 2,129,920
  unsigned short* cpk_sl = (unsigned short*)(w + 54755328);   // 2,129,920
  float* hf_sl  = (float*)(w + 56885248);                     // 65 x 65,536 = 4,259,840
  float* cf_sl  = (float*)(w + 61145088);                     // 4,259,840
  int*   barz   = (int*)  (w + 65404928);                     // arr 16,384 B + flag
  int*   arr    = barz;
  int*   flag   = barz + 4096;

  // init
  k_pack<<<768, 256, 0, stream>>>(Wx, wx_pk, 1536, 1024);
  k_pack<<<384, 256, 0, stream>>>(Wh, wh_pk, 1536, 512);
  k_pack<<<384, 256, 0, stream>>>(W_read, wr_pk, 512, 1536);
  k_misc<<<145, 256, 0, stream>>>(Wq, wq_t, barz);
  k_emb<<<2048, 256, 0, stream>>>(tgt, wemb, emb_pk);
  k_encbf<<<25600, 256, 0, stream>>>(enc, enc_bf);
  k_pre<<<12800, 256, 0, stream>>>(enc, Wc, pre_t);
  k_h0<<<32, 512, 0, stream>>>(hidden, W_init, b_init, hf_sl, hpk_sl, cf_sl, cpk_sl);

  PP p;
  p.emb = emb_pk; p.wx = wx_pk; p.wh = wh_pk; p.wr = wr_pk; p.wq = wq_t;
  p.pre = pre_t; p.enc = enc_bf;
  p.hpk = hpk_sl; p.cpk = cpk_sl;
  p.gx = gx_sl; p.gh = gh_sl; p.ro = ro_sl;
  p.hf = hf_sl; p.cf = cf_sl;
  p.Wcopy = W_copy; p.bcopy = b_copy; p.bx = bx; p.bh = bh; p.bread = b_read;
  p.wcov = w_cov; p.vatt = v_att; p.src = src;
  p.out_pred = out0; p.out_attnlast = out1; p.out_ctxf = out2;
  p.out_copypred = out3; p.out_gate = out4; p.out_covloss = out5;
  p.arr = arr; p.flag = flag;

  void* kargs[] = { (void*)&p };
  hipLaunchCooperativeKernel((const void*)k_steps, dim3(256), dim3(512), kargs, 0, stream);
}

// Round 4
// 1697.532 us; speedup vs baseline: 4.4962x; 1.5062x over previous
//
#include <hip/hip_runtime.h>
#include <cstdint>
#include <cstddef>

// RNNDecoder: B=32, T=64, S=400, V=50257, DW=DM=DE=512, DK=64, POOL=2
// Persistent cooperative kernel, 256 blocks x 512 threads, 2 barriers/step.
// Round-4: minimal recurrent critical path. In-loop GEMM = gx-ctx (K=512) +
// gh (K=512) only. emb@Wx hoisted to init (k_gxe, biases folded). readout/
// copy_gate/maxout deferred to a post-loop phase inside k_steps. Single-level
// all-gather barrier. cov + pad-mask + h(t-1) held in registers/LDS.
// Coherence scheme (validated r3): mutable cross-block data -> step-unique
// addresses, sc1 write-through stores, consumers use normal cached loads.

#define PAD_ID_C 50256

typedef float f32x4 __attribute__((ext_vector_type(4)));
typedef short bf16x8 __attribute__((ext_vector_type(8)));

__device__ __forceinline__ unsigned short f2bf(float x){
  union { float f; unsigned u; } v; v.f = x;
  unsigned r = (v.u + 0x7FFFu + ((v.u >> 16) & 1u)) >> 16;
  return (unsigned short)r;
}
__device__ __forceinline__ float bf2f(unsigned short h){
  union { unsigned u; float f; } v; v.u = ((unsigned)h) << 16; return v.f;
}
__device__ __forceinline__ float sigm_(float x){ return 1.f/(1.f+__expf(-x)); }
__device__ __forceinline__ float tanh_(float x){ float e=__expf(2.f*x); return 1.f - 2.f/(e+1.f); }

// sc1 write-through stores (bypass L2, land at IC) for cross-block data
__device__ __forceinline__ void cstf(float* p, float v){
  __hip_atomic_store(p, v, __ATOMIC_RELAXED, __HIP_MEMORY_SCOPE_AGENT);
}
__device__ __forceinline__ void csts(unsigned short* p, unsigned short v){
  __hip_atomic_store(p, v, __ATOMIC_RELAXED, __HIP_MEMORY_SCOPE_AGENT);
}

// packed A-activation index for [32][512] src -> tiles (mt,kt,lane,8)
__device__ __forceinline__ int pkidx(int b, int d){
  return ((((b>>4)*16) + (d>>5))*64 + (((d>>3)&3)*16) + (b&15))*8 + (d&7);
}

// ---------------- init kernels ----------------

__global__ void k_pack(const float* __restrict__ W, unsigned short* __restrict__ pk, int N, int K){
  int ktc = K >> 5;
  int gid = blockIdx.x*256 + threadIdx.x;
  int total = (N>>4)*ktc*64;
  if (gid >= total) return;
  int lane = gid & 63;
  int rem = gid >> 6;
  int kt = rem % ktc, nt = rem / ktc;
  int k0 = kt*32 + (lane>>4)*8;
  int n  = nt*16 + (lane&15);
  #pragma unroll
  for (int j=0;j<8;j++) pk[gid*8+j] = f2bf(W[(k0+j)*N + n]);
}

// wq transposed to [k][d] + zero the barrier region
__global__ void k_misc(const float* __restrict__ Wq, unsigned short* __restrict__ wq_t,
                       int* __restrict__ barz){
  int idx = blockIdx.x*256 + threadIdx.x;
  if (idx < 32768){ int k = idx >> 9, d = idx & 511; wq_t[idx] = f2bf(Wq[d*64+k]); }
  else if (idx < 32768 + 4112) barz[idx - 32768] = 0;
}

__global__ void k_emb(const int* __restrict__ tgt, const float* __restrict__ word_emb,
                      unsigned short* __restrict__ emb_pk){
  int bid = blockIdx.x;           // t*32+b
  int t = bid >> 5, b = bid & 31;
  int token = tgt[b*64 + t];
  const float* src = word_emb + (size_t)token*512;
  for (int d = threadIdx.x; d < 512; d += 256){
    int idx = (((t*2 + (b>>4))*16 + (d>>5))*64 + ((d>>3)&3)*16 + (b&15))*8 + (d&7);
    emb_pk[idx] = f2bf(src[d]);
  }
}

__global__ void k_encbf(const float* __restrict__ enc, unsigned short* __restrict__ enc_bf){
  int idx = blockIdx.x*256 + threadIdx.x;
  if (idx < 32*400*512) enc_bf[idx] = f2bf(enc[idx]);
}

// pre_t transposed to [b][s][64]: contiguous 128B per (b,s) row
__global__ void k_pre(const float* __restrict__ enc, const float* __restrict__ Wc,
                      unsigned short* __restrict__ pre_t){
  __shared__ float part[4][64];
  int bs = blockIdx.x;            // b*400+s
  int k = threadIdx.x & 63, dp = threadIdx.x >> 6;   // 256 threads
  const float* e = enc + (size_t)bs*512;
  float acc = 0.f;
  for (int d = dp*128; d < dp*128 + 128; d++) acc += e[d]*Wc[d*64+k];
  part[dp][k] = acc;
  __syncthreads();
  if (threadIdx.x < 64){
    float a = part[0][k] + part[1][k] + part[2][k] + part[3][k];
    pre_t[(size_t)bs*64 + k] = f2bf(a);
  }
}

// h0 = tanh(hidden@W_init + b_init) into slot-0 state arrays; ctx0 = 0
__global__ void k_h0(const float* __restrict__ hidden, const float* __restrict__ W_init,
                     const float* __restrict__ b_init,
                     float* __restrict__ hf0, unsigned short* __restrict__ hpk0,
                     float* __restrict__ cf0, unsigned short* __restrict__ cpk0){
  int b = blockIdx.x, jj = threadIdx.x;   // 32 x 512
  const float* hv = hidden + b*512;
  float acc = 0.f;
  for (int d=0; d<512; d++) acc += hv[d]*W_init[d*512+jj];
  float h = tanh_(acc + b_init[jj]);
  hf0[b*512+jj] = h;
  hpk0[pkidx(b,jj)] = f2bf(h);
  cf0[b*512+jj] = 0.f;
  cpk0[b*512+jj] = 0;   // zeros in any layout are zeros
}

// gxe = emb @ Wx[0:512] + bx + [bh;bh;0]  (hoisted out of the loop)
// M = 2048 rows (mtg = t*2+half, row-in-tile = b&15), N = 1536
__global__ void k_gxe(const unsigned short* __restrict__ emb_pk,
                      const unsigned short* __restrict__ wxe,
                      const float* __restrict__ bx, const float* __restrict__ bh,
                      float* __restrict__ gxe){
  int job = blockIdx.x*4 + (threadIdx.x>>6);   // 12288 jobs = 128 mtg x 96 nt
  int lane = threadIdx.x & 63;
  int nt = job % 96, mtg = job / 96;
  f32x4 acc = {0.f,0.f,0.f,0.f};
  const bf16x8* ae = (const bf16x8*)emb_pk + (size_t)(mtg*16)*64 + lane;
  const bf16x8* wp = (const bf16x8*)wxe + (size_t)(nt*16)*64 + lane;
  #pragma unroll
  for (int kt=0; kt<16; kt++)
    acc = __builtin_amdgcn_mfma_f32_16x16x32_bf16(ae[kt*64], wp[kt*64], acc, 0,0,0);
  int row = mtg*16 + (lane>>4)*4, col = nt*16 + (lane&15);
  float badd = bx[col] + (col < 1024 ? bh[col] : 0.f);
  #pragma unroll
  for (int i=0;i<4;i++) gxe[(size_t)(row+i)*1536 + col] = acc[i] + badd;
}

// ---------------- persistent step kernel ----------------

struct PP {
  const unsigned short *emb, *wxc, *wh, *wr, *wq, *pre, *enc;
  const float *gxe;                         // [2048][1536] emb-part + biases
  unsigned short *hpk, *cpk;                // 65 slots x 16384 shorts
  float *gx, *gh;                           // 64 slots x 49152 floats
  float *hf, *cf;                           // 65 slots x 16384 floats
  const float *Wcopy, *bcopy, *bh, *bread, *wcov, *vatt;
  const int* src;
  float *out_pred, *out_attnlast, *out_ctxf, *out_copypred, *out_gate, *out_covloss;
  int *arr;     // 256 x 16 ints (one cacheline per block)
};

// Single-level all-gather barrier: each block stores its arrival word (sc1),
// then threads 0..255 each poll one block's line. No master, no flag hop.
// Monotonic idx, arr zeroed by k_misc each launch (graph-replay safe).
__device__ __forceinline__ void gridbar(int* arr, int idx){
  asm volatile("s_waitcnt vmcnt(0) lgkmcnt(0)" ::: "memory");
  __syncthreads();
  if (threadIdx.x == 0)
    __hip_atomic_store(arr + blockIdx.x*16, idx, __ATOMIC_RELAXED, __HIP_MEMORY_SCOPE_AGENT);
  if (threadIdx.x < 256){
    while (__hip_atomic_load(arr + threadIdx.x*16, __ATOMIC_RELAXED, __HIP_MEMORY_SCOPE_AGENT) < idx)
      __builtin_amdgcn_s_sleep(1);
  }
  __syncthreads();
}

__device__ __forceinline__ float blockReduceSum(float v, float* redw, int tid){
  #pragma unroll
  for (int off=32; off; off>>=1) v += __shfl_down(v, off, 64);
  if ((tid & 63) == 0) redw[tid>>6] = v;
  __syncthreads();
  if (tid == 0){
    float r = 0.f;
    #pragma unroll
    for (int i=0;i<8;i++) r += redw[i];
    redw[8] = r;
  }
  __syncthreads();
  return redw[8];
}

__global__ __launch_bounds__(512,1) void k_steps(PP p){
  __shared__ float h_s[512];
  __shared__ float hq_part[8][64];
  __shared__ float hq_s[64];
  __shared__ float wv_s[128];
  __shared__ float p_s[400];
  __shared__ float redw[16];
  __shared__ float cred[64][65];   // stride 65 == 1 mod 32 -> conflict-free

  const int tid = threadIdx.x;
  const int b = blockIdx.x & 31, g = blockIdx.x >> 5;   // 8 g-blocks of b share an XCD
  int idx = 0;
  float c_reg = 0.f;               // coverage for s=tid (replicated per g-block)

  // hoisted invariants
  if (tid < 128) wv_s[tid] = (tid < 64) ? p.wcov[tid] : p.vatt[tid-64];
  h_s[tid] = p.hf[b*512 + tid];                       // h(-1)=h0, slot 0
  const bool padv = (tid < 400) ? (p.src[b*400+tid] == PAD_ID_C) : true;
  const float bh2r = p.bh[1024 + tid];
  const float* gxe_b = p.gxe;  // indexed per-t below
  __syncthreads();

  for (int t = 0; t < 64; ++t){
    const unsigned short* hpk_t = p.hpk + (size_t)t*16384;
    const unsigned short* cpk_t = p.cpk + (size_t)t*16384;
    float* gx_t = p.gx + (size_t)t*49152;
    float* gh_t = p.gh + (size_t)t*49152;

    // ---------------- GEMM phase: waves 0,1 of every block ----------------
    {
      int wib = tid >> 6, lane = tid & 63;
      if (wib < 2){
        int wv = wib*256 + blockIdx.x;
        if (wv < 192){        // gxc = ctx(t-1) @ Wx[512:1024]   (K=512)
          int nt = wv % 96, mt = wv / 96;
          f32x4 acc = {0.f,0.f,0.f,0.f};
          const bf16x8* wp = (const bf16x8*)p.wxc + (size_t)(nt*16)*64 + lane;
          const bf16x8* ac = (const bf16x8*)cpk_t + (size_t)(mt*16)*64 + lane;
          #pragma unroll
          for (int kt=0; kt<16; kt++)
            acc = __builtin_amdgcn_mfma_f32_16x16x32_bf16(ac[kt*64], wp[kt*64], acc, 0,0,0);
          int row = mt*16 + (lane>>4)*4, col = nt*16 + (lane&15);
          #pragma unroll
          for (int i=0;i<4;i++) cstf(&gx_t[(row+i)*1536 + col], acc[i]);
        } else if (wv < 384){ // gh = h(t-1) @ Wh                (K=512)
          int ww = wv - 192;
          int nt = ww % 96, mt = ww / 96;
          f32x4 acc = {0.f,0.f,0.f,0.f};
          const bf16x8* wp = (const bf16x8*)p.wh + (size_t)(nt*16)*64 + lane;
          const bf16x8* ah = (const bf16x8*)hpk_t + (size_t)(mt*16)*64 + lane;
          #pragma unroll
          for (int kt=0; kt<16; kt++)
            acc = __builtin_amdgcn_mfma_f32_16x16x32_bf16(ah[kt*64], wp[kt*64], acc, 0,0,0);
          int row = mt*16 + (lane>>4)*4, col = nt*16 + (lane&15);
          #pragma unroll
          for (int i=0;i<4;i++) cstf(&gh_t[(row+i)*1536 + col], acc[i]);
        }
      }
    }
    gridbar(p.arr, ++idx);

    // ---------------- ATTN phase ----------------
    float* hf_w = p.hf + (size_t)(t+1)*16384;
    unsigned short* hpk_w = p.hpk + (size_t)(t+1)*16384;
    float* cf_w = p.cf + (size_t)(t+1)*16384;
    unsigned short* cpk_w = p.cpk + (size_t)(t+1)*16384;

    // phase 0: GRU combine -> h(t)  (h(t-1) from LDS; replicated across g)
    {
      int jj = tid;
      const float* gxer = p.gxe + (size_t)((t*2 + (b>>4))*16 + (b&15))*1536;
      const float* gxr = gx_t + b*1536;
      const float* ghr = gh_t + b*1536;
      float e0 = gxer[jj], e1 = gxer[512+jj], e2 = gxer[1024+jj];
      float x0 = gxr[jj],  x1 = gxr[512+jj],  x2 = gxr[1024+jj];
      float y0 = ghr[jj],  y1 = ghr[512+jj],  y2 = ghr[1024+jj];
      float r = sigm_(e0 + x0 + y0);
      float z = sigm_(e1 + x1 + y1);
      float n = tanh_(e2 + x2 + r*(y2 + bh2r));
      float hold = h_s[jj];
      float hn = (1.f - z)*n + z*hold;
      __syncthreads();               // everyone done reading h_s(t-1)
      h_s[jj] = hn;
      if (g == 0){ cstf(&hf_w[b*512+jj], hn); csts(&hpk_w[pkidx(b,jj)], f2bf(hn)); }
    }
    __syncthreads();

    // phase 1: hq = h @ Wq (transposed wq: contiguous per-thread rows)
    {
      int k = tid & 63, pr = tid >> 6;
      const unsigned short* wrow = p.wq + k*512 + pr*64;
      float a = 0.f;
      #pragma unroll
      for (int c=0;c<8;c++){
        bf16x8 v = *(const bf16x8*)(wrow + c*8);
        #pragma unroll
        for (int j=0;j<8;j++) a += h_s[pr*64 + c*8 + j]*bf2f((unsigned short)v[j]);
      }
      hq_part[pr][k] = a;
    }
    __syncthreads();
    if (tid < 64){
      float a = 0.f;
      #pragma unroll
      for (int pr=0;pr<8;pr++) a += hq_part[pr][tid];
      hq_s[tid] = a;
    }
    __syncthreads();

    // phase 2: scores + exp (cov in register; pre row = one 128B line)
    float c_old = c_reg, p_val = 0.f;
    if (tid < 400){
      const unsigned short* prow = p.pre + ((size_t)b*400 + tid)*64;
      float a = 0.f;
      #pragma unroll
      for (int kk=0; kk<8; kk++){
        bf16x8 v = *(const bf16x8*)(prow + kk*8);
        #pragma unroll
        for (int j=0;j<8;j++){
          int k = kk*8 + j;
          float e = bf2f((unsigned short)v[j]) + hq_s[k] + c_old*wv_s[k];
          a += tanh_(e)*wv_s[64+k];
        }
      }
      p_val = padv ? 0.f : __expf(a);
      p_s[tid] = p_val;
    }
    float total = blockReduceSum((tid < 400) ? p_val : 0.f, redw, tid);
    float inv_total = 1.f/total;

    // phase 3: attn, cov (register) update, cov_loss
    float cl = 0.f;
    float inv_t = 1.f/(float)(t < 1 ? 1 : t);
    if (tid < 400){
      float attnv = p_val*inv_total;
      if (g == 0){
        p.out_copypred[((size_t)b*64 + t)*400 + tid] = attnv;
        if (t == 63) p.out_attnlast[b*400+tid] = attnv;
      }
      cl = fminf(attnv, c_old*inv_t);
      c_reg = c_old + attnv;
    }
    float cls = blockReduceSum(cl, redw, tid);
    if (g == 0 && tid == 0) p.out_covloss[b*64 + t] = cls;

    // phase 4: ctx slice (this block: 64 d), vectorized 16B loads
    {
      int dv = tid & 7, sp = tid >> 3;      // 8 d-groups x 64 s-splits
      int dgb = g*64 + dv*8;
      float acc[8] = {0.f,0.f,0.f,0.f,0.f,0.f,0.f,0.f};
      const unsigned short* ebase = p.enc + (size_t)(b*400)*512 + dgb;
      for (int ss = sp; ss < 400; ss += 64){
        bf16x8 v = *(const bf16x8*)(ebase + (size_t)ss*512);
        float pw = p_s[ss];
        #pragma unroll
        for (int j=0;j<8;j++) acc[j] += pw*bf2f((unsigned short)v[j]);
      }
      #pragma unroll
      for (int j=0;j<8;j++) cred[sp][dv*8+j] = acc[j];
    }
    __syncthreads();
    if (tid < 64){
      float cx = 0.f;
      #pragma unroll
      for (int s2=0;s2<64;s2++) cx += cred[s2][tid];
      cx *= inv_total;
      int dg = g*64 + tid;
      cstf(&cf_w[b*512+dg], cx);
      csts(&cpk_w[pkidx(b,dg)], f2bf(cx));
      if (t == 63) p.out_ctxf[b*512+dg] = cx;
    }
    gridbar(p.arr, ++idx);
  }

  // ---------------- post-loop: readout GEMM (+fused maxout) & copy_gate ----
  {
    int wslot = blockIdx.x*8 + (tid>>6);   // 0..2047
    int lane = tid & 63;

    // readout: 4096 jobs = 128 mtg x 32 nt ; K = 1536 (emb|h|ctx)
    for (int job = wslot; job < 4096; job += 2048){
      int nt = job & 31, mtg = job >> 5;
      int t = mtg >> 1, half = mtg & 1;
      f32x4 acc = {0.f,0.f,0.f,0.f};
      const bf16x8* wp = (const bf16x8*)p.wr + (size_t)(nt*48)*64 + lane;
      const bf16x8* ae = (const bf16x8*)p.emb + (size_t)(mtg*16)*64 + lane;
      const bf16x8* ah = (const bf16x8*)(p.hpk + (size_t)(t+1)*16384) + (size_t)(half*16)*64 + lane;
      const bf16x8* ac = (const bf16x8*)(p.cpk + (size_t)(t+1)*16384) + (size_t)(half*16)*64 + lane;
      #pragma unroll
      for (int kt=0; kt<16; kt++)
        acc = __builtin_amdgcn_mfma_f32_16x16x32_bf16(ae[kt*64], wp[kt*64], acc, 0,0,0);
      #pragma unroll
      for (int kt=0; kt<16; kt++)
        acc = __builtin_amdgcn_mfma_f32_16x16x32_bf16(ah[kt*64], wp[(16+kt)*64], acc, 0,0,0);
      #pragma unroll
      for (int kt=0; kt<16; kt++)
        acc = __builtin_amdgcn_mfma_f32_16x16x32_bf16(ac[kt*64], wp[(32+kt)*64], acc, 0,0,0);
      // fused bias + maxout (pairs are adjacent cols -> adjacent lanes)
      int colL = nt*16 + (lane&15);
      int b0 = half*16 + ((lane>>4)&3)*4;
      #pragma unroll
      for (int i=0;i<4;i++){
        float v = acc[i] + p.bread[colL];
        float o = __shfl_xor(v, 1, 64);
        if (!(lane & 1)){
          p.out_pred[((size_t)(b0+i)*64 + t)*256 + nt*8 + ((lane&15)>>1)] = fmaxf(v, o);
        }
      }
    }

    // copy_gate: 2048 jobs = 32 b x 64 t
    {
      int b2 = wslot >> 6, t = wslot & 63;
      const float* hfr = p.hf + (size_t)(t+1)*16384 + b2*512;
      const float* cfr = p.cf + (size_t)(t+1)*16384 + b2*512;
      float acc = 0.f;
      #pragma unroll
      for (int i=0;i<16;i++){
        int j = i*64 + lane;
        float x = (j < 512) ? hfr[j] : cfr[j-512];
        acc += x * p.Wcopy[j];
      }
      #pragma unroll
      for (int off=32; off>0; off>>=1) acc += __shfl_down(acc, off, 64);
      if (lane == 0) p.out_gate[b2*64 + t] = sigm_(acc + p.bcopy[0]);
    }
  }
}

// ---------------- host ----------------
extern "C" void kernel_launch(void* const* d_in, const int* in_sizes, int n_in,
                              void* d_out, int out_size, void* d_ws, size_t ws_size,
                              hipStream_t stream) {
  const int*   tgt     = (const int*)  d_in[0];
  const int*   src     = (const int*)  d_in[1];
  const float* enc     = (const float*)d_in[2];
  const float* hidden  = (const float*)d_in[3];
  const float* wemb    = (const float*)d_in[4];
  const float* W_init  = (const float*)d_in[5];
  const float* b_init  = (const float*)d_in[6];
  const float* Wx      = (const float*)d_in[7];
  const float* Wh      = (const float*)d_in[8];
  const float* bx      = (const float*)d_in[9];
  const float* bh      = (const float*)d_in[10];
  const float* Wc      = (const float*)d_in[11];
  const float* Wq      = (const float*)d_in[12];
  const float* w_cov   = (const float*)d_in[13];
  const float* v_att   = (const float*)d_in[14];
  const float* W_copy  = (const float*)d_in[15];
  const float* b_copy  = (const float*)d_in[16];
  const float* W_read  = (const float*)d_in[17];
  const float* b_read  = (const float*)d_in[18];

  float* out0 = (float*)d_out;            // pred [32,64,256]
  float* out1 = out0 + 524288;            // attn_last [32,400]
  float* out2 = out0 + 537088;            // ctx_f [32,512]
  float* out3 = out0 + 553472;            // copy_pred [32,64,400]
  float* out4 = out0 + 1372672;           // copy_gate [32,64,1]
  float* out5 = out0 + 1374720;           // coverage_pred [32,64]

  uint8_t* w = (uint8_t*)d_ws;
  unsigned short* emb_pk = (unsigned short*)(w);              // 2,097,152 B
  unsigned short* enc_bf = (unsigned short*)(w + 2097152);    // 13,107,200
  unsigned short* pre_t  = (unsigned short*)(w + 15204352);   // 1,638,400 ([b][s][64])
  unsigned short* wxe_pk = (unsigned short*)(w + 16842752);   // 1,572,864 (Wx rows 0:512)
  unsigned short* wxc_pk = (unsigned short*)(w + 18415616);   // 1,572,864 (Wx rows 512:1024)
  unsigned short* wh_pk  = (unsigned short*)(w + 19988480);   // 1,572,864
  unsigned short* wr_pk  = (unsigned short*)(w + 21561344);   // 1,572,864
  unsigned short* wq_t   = (unsigned short*)(w + 23134208);   // 65,536 ([k][d])
  float* gxe    = (float*)(w + 23199744);                     // 12,582,912 ([2048][1536])
  float* gx_sl  = (float*)(w + 35782656);                     // 64 x 196,608 = 12,582,912
  float* gh_sl  = (float*)(w + 48365568);                     // 12,582,912
  unsigned short* hpk_sl = (unsigned short*)(w + 60948480);   // 65 x 32,768 = 2,129,920
  unsigned short* cpk_sl = (unsigned short*)(w + 63078400);   // 2,129,920
  float* hf_sl  = (float*)(w + 65208320);                     // 65 x 65,536 = 4,259,840
  float* cf_sl  = (float*)(w + 69468160);                     // 4,259,840
  int*   arr    = (int*)  (w + 73728000);                     // 16,384 (barrier lines)

  // init
  k_pack<<<384, 256, 0, stream>>>(Wx, wxe_pk, 1536, 512);
  k_pack<<<384, 256, 0, stream>>>(Wx + (size_t)512*1536, wxc_pk, 1536, 512);
  k_pack<<<384, 256, 0, stream>>>(Wh, wh_pk, 1536, 512);
  k_pack<<<384, 256, 0, stream>>>(W_read, wr_pk, 512, 1536);
  k_misc<<<145, 256, 0, stream>>>(Wq, wq_t, arr);
  k_emb<<<2048, 256, 0, stream>>>(tgt, wemb, emb_pk);
  k_encbf<<<25600, 256, 0, stream>>>(enc, enc_bf);
  k_pre<<<12800, 256, 0, stream>>>(enc, Wc, pre_t);
  k_h0<<<32, 512, 0, stream>>>(hidden, W_init, b_init, hf_sl, hpk_sl, cf_sl, cpk_sl);
  k_gxe<<<3072, 256, 0, stream>>>(emb_pk, wxe_pk, bx, bh, gxe);

  PP p;
  p.emb = emb_pk; p.wxc = wxc_pk; p.wh = wh_pk; p.wr = wr_pk; p.wq = wq_t;
  p.pre = pre_t; p.enc = enc_bf; p.gxe = gxe;
  p.hpk = hpk_sl; p.cpk = cpk_sl;
  p.gx = gx_sl; p.gh = gh_sl;
  p.hf = hf_sl; p.cf = cf_sl;
  p.Wcopy = W_copy; p.bcopy = b_copy; p.bh = bh; p.bread = b_read;
  p.wcov = w_cov; p.vatt = v_att; p.src = src;
  p.out_pred = out0; p.out_attnlast = out1; p.out_ctxf = out2;
  p.out_copypred = out3; p.out_gate = out4; p.out_covloss = out5;
  p.arr = arr;

  void* kargs[] = { (void*)&p };
  hipLaunchCooperativeKernel((const void*)k_steps, dim3(256), dim3(512), kargs, 0, stream);
}

// Round 5
// 1688.818 us; speedup vs baseline: 4.5194x; 1.0052x over previous
//
#include <hip/hip_runtime.h>
#include <cstdint>
#include <cstddef>

// RNNDecoder: B=32, T=64, S=400, V=50257, DW=DM=DE=512, DK=64, POOL=2
// Persistent cooperative kernel, 256 blocks x 512 threads, 2 barriers/step.
// Round-5: fused gx+gh wave-jobs (pre-summed r/z gates), gxe prefetched to
// LDS by idle waves during GEMM phase, Wq in registers, distributed state/
// output stores (no straggler block), sleep-free all-gather barrier.
// Coherence (validated r3/r4): mutable cross-block data -> step-unique
// addresses, sc1 write-through stores, consumers use normal cached loads.

#define PAD_ID_C 50256

typedef float f32x4 __attribute__((ext_vector_type(4)));
typedef short bf16x8 __attribute__((ext_vector_type(8)));

__device__ __forceinline__ unsigned short f2bf(float x){
  union { float f; unsigned u; } v; v.f = x;
  unsigned r = (v.u + 0x7FFFu + ((v.u >> 16) & 1u)) >> 16;
  return (unsigned short)r;
}
__device__ __forceinline__ float bf2f(unsigned short h){
  union { unsigned u; float f; } v; v.u = ((unsigned)h) << 16; return v.f;
}
__device__ __forceinline__ float sigm_(float x){ return 1.f/(1.f+__expf(-x)); }
__device__ __forceinline__ float tanh_(float x){ float e=__expf(2.f*x); return 1.f - 2.f/(e+1.f); }

// sc1 write-through stores (bypass L2, land at IC) for cross-block data
__device__ __forceinline__ void cstf(float* p, float v){
  __hip_atomic_store(p, v, __ATOMIC_RELAXED, __HIP_MEMORY_SCOPE_AGENT);
}
__device__ __forceinline__ void csts(unsigned short* p, unsigned short v){
  __hip_atomic_store(p, v, __ATOMIC_RELAXED, __HIP_MEMORY_SCOPE_AGENT);
}

// packed A-activation index for [32][512] src -> tiles (mt,kt,lane,8)
__device__ __forceinline__ int pkidx(int b, int d){
  return ((((b>>4)*16) + (d>>5))*64 + (((d>>3)&3)*16) + (b&15))*8 + (d&7);
}

// ---------------- init kernels ----------------

__global__ void k_pack(const float* __restrict__ W, unsigned short* __restrict__ pk, int N, int K){
  int ktc = K >> 5;
  int gid = blockIdx.x*256 + threadIdx.x;
  int total = (N>>4)*ktc*64;
  if (gid >= total) return;
  int lane = gid & 63;
  int rem = gid >> 6;
  int kt = rem % ktc, nt = rem / ktc;
  int k0 = kt*32 + (lane>>4)*8;
  int n  = nt*16 + (lane&15);
  #pragma unroll
  for (int j=0;j<8;j++) pk[gid*8+j] = f2bf(W[(k0+j)*N + n]);
}

// wq transposed to [k][d] + zero the barrier region
__global__ void k_misc(const float* __restrict__ Wq, unsigned short* __restrict__ wq_t,
                       int* __restrict__ barz){
  int idx = blockIdx.x*256 + threadIdx.x;
  if (idx < 32768){ int k = idx >> 9, d = idx & 511; wq_t[idx] = f2bf(Wq[d*64+k]); }
  else if (idx < 32768 + 4112) barz[idx - 32768] = 0;
}

__global__ void k_emb(const int* __restrict__ tgt, const float* __restrict__ word_emb,
                      unsigned short* __restrict__ emb_pk){
  int bid = blockIdx.x;           // t*32+b
  int t = bid >> 5, b = bid & 31;
  int token = tgt[b*64 + t];
  const float* src = word_emb + (size_t)token*512;
  for (int d = threadIdx.x; d < 512; d += 256){
    int idx = (((t*2 + (b>>4))*16 + (d>>5))*64 + ((d>>3)&3)*16 + (b&15))*8 + (d&7);
    emb_pk[idx] = f2bf(src[d]);
  }
}

__global__ void k_encbf(const float* __restrict__ enc, unsigned short* __restrict__ enc_bf){
  int idx = blockIdx.x*256 + threadIdx.x;
  if (idx < 32*400*512) enc_bf[idx] = f2bf(enc[idx]);
}

// pre_t transposed to [b][s][64]: contiguous 128B per (b,s) row
__global__ void k_pre(const float* __restrict__ enc, const float* __restrict__ Wc,
                      unsigned short* __restrict__ pre_t){
  __shared__ float part[4][64];
  int bs = blockIdx.x;            // b*400+s
  int k = threadIdx.x & 63, dp = threadIdx.x >> 6;   // 256 threads
  const float* e = enc + (size_t)bs*512;
  float acc = 0.f;
  for (int d = dp*128; d < dp*128 + 128; d++) acc += e[d]*Wc[d*64+k];
  part[dp][k] = acc;
  __syncthreads();
  if (threadIdx.x < 64){
    float a = part[0][k] + part[1][k] + part[2][k] + part[3][k];
    pre_t[(size_t)bs*64 + k] = f2bf(a);
  }
}

// h0 = tanh(hidden@W_init + b_init) into slot-0 state arrays; ctx0 = 0
__global__ void k_h0(const float* __restrict__ hidden, const float* __restrict__ W_init,
                     const float* __restrict__ b_init,
                     float* __restrict__ hf0, unsigned short* __restrict__ hpk0,
                     float* __restrict__ cf0, unsigned short* __restrict__ cpk0){
  int b = blockIdx.x, jj = threadIdx.x;   // 32 x 512
  const float* hv = hidden + b*512;
  float acc = 0.f;
  for (int d=0; d<512; d++) acc += hv[d]*W_init[d*512+jj];
  float h = tanh_(acc + b_init[jj]);
  hf0[b*512+jj] = h;
  hpk0[pkidx(b,jj)] = f2bf(h);
  cf0[b*512+jj] = 0.f;
  cpk0[b*512+jj] = 0;   // zeros in any layout are zeros
}

// gxe = emb @ Wx[0:512] + bx + [bh;bh;0]  (hoisted out of the loop)
__global__ void k_gxe(const unsigned short* __restrict__ emb_pk,
                      const unsigned short* __restrict__ wxe,
                      const float* __restrict__ bx, const float* __restrict__ bh,
                      float* __restrict__ gxe){
  int job = blockIdx.x*4 + (threadIdx.x>>6);   // 12288 jobs = 128 mtg x 96 nt
  int lane = threadIdx.x & 63;
  int nt = job % 96, mtg = job / 96;
  f32x4 acc = {0.f,0.f,0.f,0.f};
  const bf16x8* ae = (const bf16x8*)emb_pk + (size_t)(mtg*16)*64 + lane;
  const bf16x8* wp = (const bf16x8*)wxe + (size_t)(nt*16)*64 + lane;
  #pragma unroll
  for (int kt=0; kt<16; kt++)
    acc = __builtin_amdgcn_mfma_f32_16x16x32_bf16(ae[kt*64], wp[kt*64], acc, 0,0,0);
  int row = mtg*16 + (lane>>4)*4, col = nt*16 + (lane&15);
  float badd = bx[col] + (col < 1024 ? bh[col] : 0.f);
  #pragma unroll
  for (int i=0;i<4;i++) gxe[(size_t)(row+i)*1536 + col] = acc[i] + badd;
}

// ---------------- persistent step kernel ----------------

struct PP {
  const unsigned short *emb, *wxc, *wh, *wr, *wq, *pre, *enc;
  const float *gxe;                         // [2048][1536] emb-part + biases
  unsigned short *hpk, *cpk;                // 65 slots x 16384 shorts
  float *gb;                                // 64 slots x [32][2048] gate buf
  float *hf, *cf;                           // 65 slots x 16384 floats
  const float *Wcopy, *bcopy, *bh, *bread, *wcov, *vatt;
  const int* src;
  float *out_pred, *out_attnlast, *out_ctxf, *out_copypred, *out_gate, *out_covloss;
  int *arr;     // 256 x 16 ints (one cacheline per block)
};

// Sleep-free all-gather barrier: each block stores its arrival word (sc1);
// threads 0..255 each poll one block's line. Monotonic idx; arr zeroed by
// k_misc each launch (graph-replay safe). Entry waitcnt drains sc1 data
// stores of every wave before arrival.
__device__ __forceinline__ void gridbar(int* arr, int idx){
  asm volatile("s_waitcnt vmcnt(0) lgkmcnt(0)" ::: "memory");
  __syncthreads();
  if (threadIdx.x == 0)
    __hip_atomic_store(arr + blockIdx.x*16, idx, __ATOMIC_RELAXED, __HIP_MEMORY_SCOPE_AGENT);
  if (threadIdx.x < 256){
    while (__hip_atomic_load(arr + threadIdx.x*16, __ATOMIC_RELAXED, __HIP_MEMORY_SCOPE_AGENT) < idx){}
  }
  __syncthreads();
}

__device__ __forceinline__ float blockReduceSum(float v, float* redw, int tid){
  #pragma unroll
  for (int off=32; off; off>>=1) v += __shfl_down(v, off, 64);
  if ((tid & 63) == 0) redw[tid>>6] = v;
  __syncthreads();
  if (tid == 0){
    float r = 0.f;
    #pragma unroll
    for (int i=0;i<8;i++) r += redw[i];
    redw[8] = r;
  }
  __syncthreads();
  return redw[8];
}

__global__ __launch_bounds__(512,1) void k_steps(PP p){
  __shared__ float h_s[512];
  __shared__ float gxe_s[1536];
  __shared__ float hq_part[8][64];
  __shared__ float hq_s[64];
  __shared__ float wv_s[128];
  __shared__ float p_s[400];
  __shared__ float redw[16];
  __shared__ float cred[64][65];   // stride 65 == 1 mod 32

  const int tid = threadIdx.x;
  const int b = blockIdx.x & 31, g = blockIdx.x >> 5;
  int idx = 0;
  float c_reg = 0.f;               // coverage for s=tid (replicated per g-block)

  // hoisted invariants
  if (tid < 128) wv_s[tid] = (tid < 64) ? p.wcov[tid] : p.vatt[tid-64];
  h_s[tid] = p.hf[b*512 + tid];                       // h(-1)=h0, slot 0
  const bool padv = (tid < 400) ? (p.src[b*400+tid] == PAD_ID_C) : true;
  const float bh2r = p.bh[1024 + tid];
  const int sown = tid/50 == g ? 1 : 0;               // owner of s=tid outputs
  bf16x8 wqreg[8];                                    // Wq row slice, constant
  {
    int k = tid & 63, pr = tid >> 6;
    const bf16x8* wrow = (const bf16x8*)(p.wq + k*512 + pr*64);
    #pragma unroll
    for (int c=0;c<8;c++) wqreg[c] = wrow[c];
  }
  __syncthreads();

  for (int t = 0; t < 64; ++t){
    const unsigned short* hpk_t = p.hpk + (size_t)t*16384;
    const unsigned short* cpk_t = p.cpk + (size_t)t*16384;
    float* gb_t = p.gb + (size_t)t*65536;

    // ------- GEMM phase: wave 0 of blocks 0..191 (fused gx+gh job);
    // ------- waves 1..7 of all blocks prefetch gxe row into LDS.
    {
      int wib = tid >> 6, lane = tid & 63;
      if (wib == 0){
        if (blockIdx.x < 192){
          int nt = blockIdx.x % 96, mt = blockIdx.x / 96;
          f32x4 aX = {0.f,0.f,0.f,0.f}, aH = {0.f,0.f,0.f,0.f};
          const bf16x8* wpX = (const bf16x8*)p.wxc + (size_t)(nt*16)*64 + lane;
          const bf16x8* wpH = (const bf16x8*)p.wh  + (size_t)(nt*16)*64 + lane;
          const bf16x8* ac = (const bf16x8*)cpk_t + (size_t)(mt*16)*64 + lane;
          const bf16x8* ah = (const bf16x8*)hpk_t + (size_t)(mt*16)*64 + lane;
          #pragma unroll
          for (int kt=0; kt<16; kt++){
            aX = __builtin_amdgcn_mfma_f32_16x16x32_bf16(ac[kt*64], wpX[kt*64], aX, 0,0,0);
            aH = __builtin_amdgcn_mfma_f32_16x16x32_bf16(ah[kt*64], wpH[kt*64], aH, 0,0,0);
          }
          int row = mt*16 + (lane>>4)*4, col = nt*16 + (lane&15);
          if (col < 1024){
            #pragma unroll
            for (int i=0;i<4;i++) cstf(&gb_t[(row+i)*2048 + col], aX[i]+aH[i]);
          } else {
            #pragma unroll
            for (int i=0;i<4;i++){
              cstf(&gb_t[(row+i)*2048 + col], aX[i]);
              cstf(&gb_t[(row+i)*2048 + col + 512], aH[i]);
            }
          }
        }
      } else {
        const float* gxer = p.gxe + (size_t)((t*2 + (b>>4))*16 + (b&15))*1536;
        for (int i = tid - 64; i < 1536; i += 448) gxe_s[i] = gxer[i];
      }
    }
    gridbar(p.arr, ++idx);

    // ---------------- ATTN phase ----------------
    float* hf_w = p.hf + (size_t)(t+1)*16384;
    unsigned short* hpk_w = p.hpk + (size_t)(t+1)*16384;
    float* cf_w = p.cf + (size_t)(t+1)*16384;
    unsigned short* cpk_w = p.cpk + (size_t)(t+1)*16384;

    // phase 0: GRU combine -> h(t); state writes distributed (wave g stores)
    {
      int jj = tid;
      const float* gbr = gb_t + b*2048;
      float s0 = gbr[jj], s1 = gbr[512+jj], x2 = gbr[1024+jj], y2 = gbr[1536+jj];
      float e0 = gxe_s[jj], e1 = gxe_s[512+jj], e2 = gxe_s[1024+jj];
      float r = sigm_(e0 + s0);
      float z = sigm_(e1 + s1);
      float n = tanh_(e2 + x2 + r*(y2 + bh2r));
      float hold = h_s[jj];
      float hn = (1.f - z)*n + z*hold;
      __syncthreads();               // everyone done reading h_s(t-1)
      h_s[jj] = hn;
      if ((tid>>6) == g){ cstf(&hf_w[b*512+jj], hn); csts(&hpk_w[pkidx(b,jj)], f2bf(hn)); }
    }
    __syncthreads();

    // phase 1: hq = h @ Wq (weights in registers; h_s broadcast reads)
    {
      int k = tid & 63, pr = tid >> 6;
      float a = 0.f;
      #pragma unroll
      for (int c=0;c<8;c++){
        #pragma unroll
        for (int j=0;j<8;j++) a += h_s[pr*64 + c*8 + j]*bf2f((unsigned short)wqreg[c][j]);
      }
      hq_part[pr][k] = a;
    }
    __syncthreads();
    if (tid < 64){
      float a = 0.f;
      #pragma unroll
      for (int pr=0;pr<8;pr++) a += hq_part[pr][tid];
      hq_s[tid] = a;
    }
    __syncthreads();

    // phase 2: scores + exp (cov in register; pre row = one 128B line)
    float c_old = c_reg, p_val = 0.f;
    if (tid < 400){
      const unsigned short* prow = p.pre + ((size_t)b*400 + tid)*64;
      float a = 0.f;
      #pragma unroll
      for (int kk=0; kk<8; kk++){
        bf16x8 v = *(const bf16x8*)(prow + kk*8);
        #pragma unroll
        for (int j=0;j<8;j++){
          int k = kk*8 + j;
          float e = bf2f((unsigned short)v[j]) + hq_s[k] + c_old*wv_s[k];
          a += tanh_(e)*wv_s[64+k];
        }
      }
      p_val = padv ? 0.f : __expf(a);
      p_s[tid] = p_val;
    }
    float total = blockReduceSum((tid < 400) ? p_val : 0.f, redw, tid);
    float inv_total = 1.f/total;

    // phase 3: attn, cov (register) update, cov_loss; output writes sliced
    float cl = 0.f;
    float inv_t = 1.f/(float)(t < 1 ? 1 : t);
    if (tid < 400){
      float attnv = p_val*inv_total;
      if (sown){
        p.out_copypred[((size_t)b*64 + t)*400 + tid] = attnv;
        if (t == 63) p.out_attnlast[b*400+tid] = attnv;
      }
      cl = fminf(attnv, c_old*inv_t);
      c_reg = c_old + attnv;
    }
    float cls = blockReduceSum(cl, redw, tid);
    if (g == 0 && tid == 0) p.out_covloss[b*64 + t] = cls;

    // phase 4: ctx slice (this block: 64 d), vectorized 16B loads
    {
      int dv = tid & 7, sp = tid >> 3;      // 8 d-groups x 64 s-splits
      int dgb = g*64 + dv*8;
      float acc[8] = {0.f,0.f,0.f,0.f,0.f,0.f,0.f,0.f};
      const unsigned short* ebase = p.enc + (size_t)(b*400)*512 + dgb;
      for (int ss = sp; ss < 400; ss += 64){
        bf16x8 v = *(const bf16x8*)(ebase + (size_t)ss*512);
        float pw = p_s[ss];
        #pragma unroll
        for (int j=0;j<8;j++) acc[j] += pw*bf2f((unsigned short)v[j]);
      }
      #pragma unroll
      for (int j=0;j<8;j++) cred[sp][dv*8+j] = acc[j];
    }
    __syncthreads();
    if (tid < 64){
      float cx = 0.f;
      #pragma unroll
      for (int s2=0;s2<64;s2++) cx += cred[s2][tid];
      cx *= inv_total;
      int dg = g*64 + tid;
      cstf(&cf_w[b*512+dg], cx);
      csts(&cpk_w[pkidx(b,dg)], f2bf(cx));
      if (t == 63) p.out_ctxf[b*512+dg] = cx;
    }
    gridbar(p.arr, ++idx);
  }

  // ---------------- post-loop: readout GEMM (+fused maxout) & copy_gate ----
  {
    int wslot = blockIdx.x*8 + (tid>>6);   // 0..2047
    int lane = tid & 63;

    // readout: 4096 jobs = 128 mtg x 32 nt ; K = 1536 (emb|h|ctx)
    for (int job = wslot; job < 4096; job += 2048){
      int nt = job & 31, mtg = job >> 5;
      int t = mtg >> 1, half = mtg & 1;
      f32x4 acc = {0.f,0.f,0.f,0.f};
      const bf16x8* wp = (const bf16x8*)p.wr + (size_t)(nt*48)*64 + lane;
      const bf16x8* ae = (const bf16x8*)p.emb + (size_t)(mtg*16)*64 + lane;
      const bf16x8* ah = (const bf16x8*)(p.hpk + (size_t)(t+1)*16384) + (size_t)(half*16)*64 + lane;
      const bf16x8* ac = (const bf16x8*)(p.cpk + (size_t)(t+1)*16384) + (size_t)(half*16)*64 + lane;
      #pragma unroll
      for (int kt=0; kt<16; kt++)
        acc = __builtin_amdgcn_mfma_f32_16x16x32_bf16(ae[kt*64], wp[kt*64], acc, 0,0,0);
      #pragma unroll
      for (int kt=0; kt<16; kt++)
        acc = __builtin_amdgcn_mfma_f32_16x16x32_bf16(ah[kt*64], wp[(16+kt)*64], acc, 0,0,0);
      #pragma unroll
      for (int kt=0; kt<16; kt++)
        acc = __builtin_amdgcn_mfma_f32_16x16x32_bf16(ac[kt*64], wp[(32+kt)*64], acc, 0,0,0);
      int colL = nt*16 + (lane&15);
      int b0 = half*16 + (lane>>4)*4;
      #pragma unroll
      for (int i=0;i<4;i++){
        float v = acc[i] + p.bread[colL];
        float o = __shfl_xor(v, 1, 64);
        if (!(lane & 1)){
          p.out_pred[((size_t)(b0+i)*64 + t)*256 + nt*8 + ((lane&15)>>1)] = fmaxf(v, o);
        }
      }
    }

    // copy_gate: 2048 jobs = 32 b x 64 t
    {
      int b2 = wslot >> 6, t = wslot & 63;
      const float* hfr = p.hf + (size_t)(t+1)*16384 + b2*512;
      const float* cfr = p.cf + (size_t)(t+1)*16384 + b2*512;
      float acc = 0.f;
      #pragma unroll
      for (int i=0;i<16;i++){
        int j = i*64 + lane;
        float x = (j < 512) ? hfr[j] : cfr[j-512];
        acc += x * p.Wcopy[j];
      }
      #pragma unroll
      for (int off=32; off>0; off>>=1) acc += __shfl_down(acc, off, 64);
      if (lane == 0) p.out_gate[b2*64 + t] = sigm_(acc + p.bcopy[0]);
    }
  }
}

// ---------------- host ----------------
extern "C" void kernel_launch(void* const* d_in, const int* in_sizes, int n_in,
                              void* d_out, int out_size, void* d_ws, size_t ws_size,
                              hipStream_t stream) {
  const int*   tgt     = (const int*)  d_in[0];
  const int*   src     = (const int*)  d_in[1];
  const float* enc     = (const float*)d_in[2];
  const float* hidden  = (const float*)d_in[3];
  const float* wemb    = (const float*)d_in[4];
  const float* W_init  = (const float*)d_in[5];
  const float* b_init  = (const float*)d_in[6];
  const float* Wx      = (const float*)d_in[7];
  const float* Wh      = (const float*)d_in[8];
  const float* bx      = (const float*)d_in[9];
  const float* bh      = (const float*)d_in[10];
  const float* Wc      = (const float*)d_in[11];
  const float* Wq      = (const float*)d_in[12];
  const float* w_cov   = (const float*)d_in[13];
  const float* v_att   = (const float*)d_in[14];
  const float* W_copy  = (const float*)d_in[15];
  const float* b_copy  = (const float*)d_in[16];
  const float* W_read  = (const float*)d_in[17];
  const float* b_read  = (const float*)d_in[18];

  float* out0 = (float*)d_out;            // pred [32,64,256]
  float* out1 = out0 + 524288;            // attn_last [32,400]
  float* out2 = out0 + 537088;            // ctx_f [32,512]
  float* out3 = out0 + 553472;            // copy_pred [32,64,400]
  float* out4 = out0 + 1372672;           // copy_gate [32,64,1]
  float* out5 = out0 + 1374720;           // coverage_pred [32,64]

  uint8_t* w = (uint8_t*)d_ws;
  unsigned short* emb_pk = (unsigned short*)(w);              // 2,097,152 B
  unsigned short* enc_bf = (unsigned short*)(w + 2097152);    // 13,107,200
  unsigned short* pre_t  = (unsigned short*)(w + 15204352);   // 1,638,400 ([b][s][64])
  unsigned short* wxe_pk = (unsigned short*)(w + 16842752);   // 1,572,864 (Wx rows 0:512)
  unsigned short* wxc_pk = (unsigned short*)(w + 18415616);   // 1,572,864 (Wx rows 512:1024)
  unsigned short* wh_pk  = (unsigned short*)(w + 19988480);   // 1,572,864
  unsigned short* wr_pk  = (unsigned short*)(w + 21561344);   // 1,572,864
  unsigned short* wq_t   = (unsigned short*)(w + 23134208);   // 65,536 ([k][d])
  float* gxe    = (float*)(w + 23199744);                     // 12,582,912 ([2048][1536])
  float* gb_sl  = (float*)(w + 35782656);                     // 64 x 262,144 = 16,777,216
  unsigned short* hpk_sl = (unsigned short*)(w + 52559872);   // 65 x 32,768 = 2,129,920
  unsigned short* cpk_sl = (unsigned short*)(w + 54689792);   // 2,129,920
  float* hf_sl  = (float*)(w + 56819712);                     // 65 x 65,536 = 4,259,840
  float* cf_sl  = (float*)(w + 61079552);                     // 4,259,840
  int*   arr    = (int*)  (w + 65339392);                     // 16,384 (barrier lines)

  // init
  k_pack<<<384, 256, 0, stream>>>(Wx, wxe_pk, 1536, 512);
  k_pack<<<384, 256, 0, stream>>>(Wx + (size_t)512*1536, wxc_pk, 1536, 512);
  k_pack<<<384, 256, 0, stream>>>(Wh, wh_pk, 1536, 512);
  k_pack<<<384, 256, 0, stream>>>(W_read, wr_pk, 512, 1536);
  k_misc<<<145, 256, 0, stream>>>(Wq, wq_t, arr);
  k_emb<<<2048, 256, 0, stream>>>(tgt, wemb, emb_pk);
  k_encbf<<<25600, 256, 0, stream>>>(enc, enc_bf);
  k_pre<<<12800, 256, 0, stream>>>(enc, Wc, pre_t);
  k_h0<<<32, 512, 0, stream>>>(hidden, W_init, b_init, hf_sl, hpk_sl, cf_sl, cpk_sl);
  k_gxe<<<3072, 256, 0, stream>>>(emb_pk, wxe_pk, bx, bh, gxe);

  PP p;
  p.emb = emb_pk; p.wxc = wxc_pk; p.wh = wh_pk; p.wr = wr_pk; p.wq = wq_t;
  p.pre = pre_t; p.enc = enc_bf; p.gxe = gxe;
  p.hpk = hpk_sl; p.cpk = cpk_sl;
  p.gb = gb_sl;
  p.hf = hf_sl; p.cf = cf_sl;
  p.Wcopy = W_copy; p.bcopy = b_copy; p.bh = bh; p.bread = b_read;
  p.wcov = w_cov; p.vatt = v_att; p.src = src;
  p.out_pred = out0; p.out_attnlast = out1; p.out_ctxf = out2;
  p.out_copypred = out3; p.out_gate = out4; p.out_covloss = out5;
  p.arr = arr;

  void* kargs[] = { (void*)&p };
  hipLaunchCooperativeKernel((const void*)k_steps, dim3(256), dim3(512), kargs, 0, stream);
}